// Round 8
// baseline (1557.122 us; speedup 1.0000x reference)
//
#include <hip/hip_runtime.h>
#include <math.h>

// Net: ConvLSTM(32)->pool->ConvLSTM(48)->pool->conv3+ELU->conv4(1x1)+ELU->conv5(1x1)
// B=8, T=32, H=8, W=256, F1=32, F2=48, F3=256, F4=128, NNOTE=88
// R8: persistent LSTM kernels with REGULAR launches (grid=256=#CUs, co-residency
//     by capacity: lstm1 512thr/2-per-CU-capacity, lstm2 256thr/1-per-CU) and a
//     hand-rolled device-scope grid barrier. Fixed LDS clear/stage race.

#define DEVINL static __device__ __forceinline__
typedef __attribute__((ext_vector_type(8))) short short8;
typedef __attribute__((ext_vector_type(4))) float f32x4;

#define PLANE_W3 2359296    // w3F (16*48*6*4*16*8), hi plane size (lo follows)

DEVINL float sigm(float x) { return 1.0f / (1.0f + __expf(-x)); }
DEVINL float tanh_fast(float x) { return 1.0f - 2.0f / (__expf(2.0f * x) + 1.0f); }
DEVINL float elu(float x) { return x > 0.0f ? x : expm1f(x); }
DEVINL unsigned short bf16_rne(float v) {
    unsigned u = __float_as_uint(v);
    unsigned r = (u + 0x7FFF + ((u >> 16) & 1)) >> 16;
    return (unsigned short)r;
}
DEVINL float bf16_to_f(unsigned short h) { return __uint_as_float(((unsigned)h) << 16); }
DEVINL unsigned pack_hl(float v) {
    unsigned short hi = bf16_rne(v);
    unsigned short lo = bf16_rne(v - bf16_to_f(hi));
    return (unsigned)hi | ((unsigned)lo << 16);
}

// device-scope grid barrier: leaders atomicAdd a counter, spin to phase target.
// Requires all blocks co-resident (grid <= capacity; see launch comments).
// __threadfence emits agent-scope L2 wb/inv -> cross-XCD visibility.
DEVINL void gridbar(unsigned* cnt, unsigned nblk, unsigned* phase) {
    __syncthreads();
    if (threadIdx.x == 0) {
        __threadfence();                      // release
        atomicAdd(cnt, 1u);
        unsigned target = (++(*phase)) * nblk;
        while (__hip_atomic_load(cnt, __ATOMIC_RELAXED, __HIP_MEMORY_SCOPE_AGENT) < target)
            __builtin_amdgcn_s_sleep(4);
        __threadfence();                      // acquire
    }
    __syncthreads();
}

// ---------------- LSTM1: all 32 steps, persistent ----------------
// grid (4,8,8) = (xq, y, b) = 256 blocks, block 512 = 8 waves = (mh 4) x (nh 2).
// A-frags (2-term hi-only) resident in VGPRs; c in registers (block-private).
__global__ __launch_bounds__(512, 2) void lstm1_all(
    const float* __restrict__ xin,           // (8,1,32,8,256)
    const unsigned short* __restrict__ w1F,  // hi, [dx][mt][kk][kg][ln][8]
    const float* __restrict__ b1,            // (128)
    float* __restrict__ hb0, float* __restrict__ hb1, float* __restrict__ hb2,
    unsigned* __restrict__ p1pk,             // (8,32,16,4,128) packed hi|lo<<16
    unsigned* __restrict__ barcnt)
{
    __shared__ __align__(16) unsigned short sBhi[66 * 128];
    __shared__ __align__(16) unsigned short sBlo[66 * 128];
    const int xq = blockIdx.x, y = blockIdx.y, b = blockIdx.z;
    const int x0 = xq * 64;
    const int tid = threadIdx.x;
    const int l = tid & 63;
    const int wv = __builtin_amdgcn_readfirstlane(tid >> 6);
    const int mh = wv >> 1, nh = wv & 1;
    const int ln = l & 15, kg = l >> 4;

    // resident A fragments: [mtl][kk][dx], 24 x 16B = 96 VGPR
    short8 aReg[2][4][3];
#pragma unroll
    for (int mtl = 0; mtl < 2; ++mtl)
#pragma unroll
        for (int kk = 0; kk < 4; ++kk)
#pragma unroll
            for (int dx = 0; dx < 3; ++dx)
                aReg[mtl][kk][dx] = *(const short8*)
                    &w1F[((((dx * 8 + mh * 2 + mtl) * 4 + kk) * 4 + kg) * 16 + ln) * 8];

    // per-lane biases and cell state
    float bi[2], bff[2], bg[2], bo[2], cReg[2][2];
#pragma unroll
    for (int mtl = 0; mtl < 2; ++mtl) {
        int f = (mh * 2 + mtl) * 4 + kg;
        bi[mtl] = b1[f]; bff[mtl] = b1[32 + f];
        bg[mtl] = b1[64 + f]; bo[mtl] = b1[96 + f];
        cReg[mtl][0] = 0.f; cReg[mtl][1] = 0.f;
    }

    // zero LDS once (covers k-pad rows 99..127), then sync before staging
    for (int e = tid; e < 66 * 128; e += 512) { sBhi[e] = 0; sBlo[e] = 0; }
    __syncthreads();

    float* hout  = hb0;   // t%3
    float* hpool = hb1;   // (t+1)%3 : h of t-2
    float* hprev = hb2;   // (t+2)%3 : h of t-1 (zeroed for t=0)
    unsigned phase = 0;

    for (int t = 0; t < 32; ++t) {
        if (t) gridbar(barcnt, 256, &phase);

        // fused pool of pair (t-2, t-1) -> p1[tp], odd-y blocks
        if (((t & 1) == 0) && t >= 2 && (y & 1) == 1) {
            int tp = (t >> 1) - 1, yp = y >> 1;
            for (int e = tid; e < 1024; e += 512) {
                int f = e >> 5, xl = e & 31;
                int xp = (x0 >> 1) + xl, gx = x0 + 2 * xl;
                int b0 = ((b * 32 + f) * 8 + (y - 1)) * 256 + gx;
                float m = hpool[b0];
                m = fmaxf(m, hpool[b0 + 1]);
                m = fmaxf(m, hpool[b0 + 256]);
                m = fmaxf(m, hpool[b0 + 257]);
                m = fmaxf(m, hprev[b0]);
                m = fmaxf(m, hprev[b0 + 1]);
                m = fmaxf(m, hprev[b0 + 256]);
                m = fmaxf(m, hprev[b0 + 257]);
                p1pk[(((b * 32 + f) * 16 + tp) * 4 + yp) * 128 + xp] = pack_hl(m);
            }
        }

        // stage input tile (kk < 99 only; pads stay zero)
        for (int e = tid; e < 66 * 99; e += 512) {
            int lx = e % 66, kk = e / 66;
            int ci = kk / 3, dy = kk - ci * 3;
            int gy = y + dy - 1, gx = x0 + lx - 1;
            float v = 0.0f;
            if (gy >= 0 && gy < 8 && gx >= 0 && gx < 256)
                v = (ci == 0) ? xin[((b * 32 + t) * 8 + gy) * 256 + gx]
                              : hprev[((b * 32 + (ci - 1)) * 8 + gy) * 256 + gx];
            unsigned short hi = bf16_rne(v);
            unsigned short lo = bf16_rne(v - bf16_to_f(hi));
            int a16 = lx * 128 + (((kk >> 3) ^ (lx & 15)) << 3) + (kk & 7);
            sBhi[a16] = hi;
            sBlo[a16] = lo;
        }
        __syncthreads();

        f32x4 acc[2][2];
#pragma unroll
        for (int i = 0; i < 2; ++i)
#pragma unroll
            for (int j = 0; j < 2; ++j) acc[i][j] = (f32x4){0.f, 0.f, 0.f, 0.f};

#pragma unroll
        for (int kk = 0; kk < 4; ++kk) {
            short8 bh[2][3], bl[2][3];
#pragma unroll
            for (int ntl = 0; ntl < 2; ++ntl)
#pragma unroll
                for (int dx = 0; dx < 3; ++dx) {
                    int lx = (nh * 2 + ntl) * 16 + ln + dx;
                    int slot = kk * 4 + kg;
                    int boff = lx * 128 + ((slot ^ (lx & 15)) << 3);
                    bh[ntl][dx] = *(const short8*)&sBhi[boff];
                    bl[ntl][dx] = *(const short8*)&sBlo[boff];
                }
#pragma unroll
            for (int mtl = 0; mtl < 2; ++mtl)
#pragma unroll
                for (int dx = 0; dx < 3; ++dx) {
                    short8 ah = aReg[mtl][kk][dx];
#pragma unroll
                    for (int ntl = 0; ntl < 2; ++ntl) {
                        acc[mtl][ntl] = __builtin_amdgcn_mfma_f32_16x16x32_bf16(ah, bl[ntl][dx], acc[mtl][ntl], 0, 0, 0);
                        acc[mtl][ntl] = __builtin_amdgcn_mfma_f32_16x16x32_bf16(ah, bh[ntl][dx], acc[mtl][ntl], 0, 0, 0);
                    }
                }
        }
        __syncthreads();   // sB reused next step

#pragma unroll
        for (int mtl = 0; mtl < 2; ++mtl) {
            const int f = (mh * 2 + mtl) * 4 + kg;
#pragma unroll
            for (int ntl = 0; ntl < 2; ++ntl) {
                f32x4 a = acc[mtl][ntl];
                int gidx = ((b * 32 + f) * 8 + y) * 256 + x0 + (nh * 2 + ntl) * 16 + ln;
                float zi = a[0] + bi[mtl], zf = a[1] + bff[mtl];
                float zg = a[2] + bg[mtl], zo = a[3] + bo[mtl];
                float cn = sigm(zf) * cReg[mtl][ntl] + sigm(zi) * tanh_fast(zg);
                cReg[mtl][ntl] = cn;
                hout[gidx] = sigm(zo) * tanh_fast(cn);
            }
        }

        float* tmp = hout; hout = hpool; hpool = hprev; hprev = tmp;
    }

    // final pool: pair (t=30, t=31) = (hpool, hprev), tp = 15
    gridbar(barcnt, 256, &phase);
    if ((y & 1) == 1) {
        int yp = y >> 1;
        for (int e = tid; e < 1024; e += 512) {
            int f = e >> 5, xl = e & 31;
            int xp = (x0 >> 1) + xl, gx = x0 + 2 * xl;
            int b0 = ((b * 32 + f) * 8 + (y - 1)) * 256 + gx;
            float m = hpool[b0];
            m = fmaxf(m, hpool[b0 + 1]);
            m = fmaxf(m, hpool[b0 + 256]);
            m = fmaxf(m, hpool[b0 + 257]);
            m = fmaxf(m, hprev[b0]);
            m = fmaxf(m, hprev[b0 + 1]);
            m = fmaxf(m, hprev[b0 + 256]);
            m = fmaxf(m, hprev[b0 + 257]);
            p1pk[(((b * 32 + f) * 16 + 15) * 4 + yp) * 128 + xp] = pack_hl(m);
        }
    }
}

// ---------------- LSTM2: all 16 steps, persistent ----------------
// grid (8,4,8) = 256 blocks, block 256 = 4 waves; wave wv owns mt = wv*3..+2.
// 72 A-frags resident (288 VGPR @ 1 wave/SIMD); c2 in registers.
__global__ __launch_bounds__(256, 1) void lstm2_all(
    const unsigned* __restrict__ p1pk,
    const unsigned short* __restrict__ w2F,  // hi, [dx][mt][kk][kg][ln][8]
    const float* __restrict__ b2,            // (192)
    float* __restrict__ hb0, float* __restrict__ hb1, float* __restrict__ hb2,
    unsigned short* __restrict__ p2hi, unsigned short* __restrict__ p2lo,
    unsigned* __restrict__ barcnt)
{
    __shared__ __align__(16) unsigned short sBhi[18 * 256];
    __shared__ __align__(16) unsigned short sBlo[18 * 256];
    const int xq = blockIdx.x, y = blockIdx.y, b = blockIdx.z;
    const int x0 = xq * 16;
    const int tid = threadIdx.x;
    const int l = tid & 63;
    const int wv = __builtin_amdgcn_readfirstlane(tid >> 6);
    const int ln = l & 15, kg = l >> 4;

    // resident A fragments: [j][kk][dx], 72 x 16B = 288 VGPR
    short8 aReg[3][8][3];
#pragma unroll
    for (int j = 0; j < 3; ++j)
#pragma unroll
        for (int kk = 0; kk < 8; ++kk)
#pragma unroll
            for (int dx = 0; dx < 3; ++dx)
                aReg[j][kk][dx] = *(const short8*)
                    &w2F[((((dx * 12 + wv * 3 + j) * 8 + kk) * 4 + kg) * 16 + ln) * 8];

    float bi[3], bff[3], bg[3], bo[3], cReg[3];
#pragma unroll
    for (int j = 0; j < 3; ++j) {
        int f = (wv * 3 + j) * 4 + kg;
        bi[j] = b2[f]; bff[j] = b2[48 + f];
        bg[j] = b2[96 + f]; bo[j] = b2[144 + f];
        cReg[j] = 0.f;
    }

    for (int e = tid; e < 18 * 256; e += 256) { sBhi[e] = 0; sBlo[e] = 0; }
    __syncthreads();

    float* hout  = hb0;
    float* hpool = hb1;
    float* hprev = hb2;   // zeroed
    unsigned phase = 0;

    for (int t = 0; t < 16; ++t) {
        if (t) gridbar(barcnt, 256, &phase);

        // fused pool of h2 pair (t-2, t-1) -> p2[tp]; y<2 blocks
        if (((t & 1) == 0) && t >= 2 && y < 2) {
            int tp = (t >> 1) - 1;
            for (int e = tid; e < 48 * 8; e += 256) {
                int f = e >> 3, xl = e & 7;
                int xp = xq * 8 + xl;
                int g0 = ((b * 48 + f) * 4 + y * 2) * 128 + xp * 2;
                float m = fmaxf(fmaxf(hpool[g0], hpool[g0 + 1]),
                                fmaxf(hpool[g0 + 128], hpool[g0 + 129]));
                m = fmaxf(m, fmaxf(fmaxf(hprev[g0], hprev[g0 + 1]),
                                   fmaxf(hprev[g0 + 128], hprev[g0 + 129])));
                int pi = ((b * 48 + f) * 16 + tp * 2 + y) * 64 + xp;
                unsigned short hi = bf16_rne(m);
                p2hi[pi] = hi;
                p2lo[pi] = bf16_rne(m - bf16_to_f(hi));
            }
        }

        for (int idx = tid; idx < 80 * 54; idx += 256) {
            int ci = idx / 54, rem = idx % 54;
            int dy = rem / 18, lx = rem % 18;
            int gy = y + dy - 1, gx = x0 + lx - 1;
            unsigned short hi = 0, lo = 0;
            if (gy >= 0 && gy < 4 && gx >= 0 && gx < 128) {
                if (ci < 32) {
                    unsigned v = p1pk[(((b * 32 + ci) * 16 + t) * 4 + gy) * 128 + gx];
                    hi = (unsigned short)v;
                    lo = (unsigned short)(v >> 16);
                } else {
                    float v = hprev[((b * 48 + (ci - 32)) * 4 + gy) * 128 + gx];
                    hi = bf16_rne(v);
                    lo = bf16_rne(v - bf16_to_f(hi));
                }
            }
            int k = ci * 3 + dy;
            int a16 = lx * 256 + (((k >> 3) ^ (lx & 15)) << 3) + (k & 7);
            sBhi[a16] = hi;
            sBlo[a16] = lo;
        }
        __syncthreads();

        f32x4 acc[3] = {{0.f,0.f,0.f,0.f},{0.f,0.f,0.f,0.f},{0.f,0.f,0.f,0.f}};
#pragma unroll
        for (int kk = 0; kk < 8; ++kk) {
            short8 bh[3], bl[3];
#pragma unroll
            for (int dx = 0; dx < 3; ++dx) {
                int lx = ln + dx;
                int boff = lx * 256 + ((((kk << 2) + kg) ^ (lx & 15)) << 3);
                bh[dx] = *(const short8*)&sBhi[boff];
                bl[dx] = *(const short8*)&sBlo[boff];
            }
#pragma unroll
            for (int j = 0; j < 3; ++j)
#pragma unroll
                for (int dx = 0; dx < 3; ++dx) {
                    short8 ah = aReg[j][kk][dx];
                    acc[j] = __builtin_amdgcn_mfma_f32_16x16x32_bf16(ah, bl[dx], acc[j], 0, 0, 0);
                    acc[j] = __builtin_amdgcn_mfma_f32_16x16x32_bf16(ah, bh[dx], acc[j], 0, 0, 0);
                }
        }
        __syncthreads();

        const int x = x0 + ln;
#pragma unroll
        for (int j = 0; j < 3; ++j) {
            int f = (wv * 3 + j) * 4 + kg;
            float zi = acc[j][0] + bi[j];
            float zf = acc[j][1] + bff[j];
            float zg = acc[j][2] + bg[j];
            float zo = acc[j][3] + bo[j];
            float cn = sigm(zf) * cReg[j] + sigm(zi) * tanh_fast(zg);
            cReg[j] = cn;
            hout[((b * 48 + f) * 4 + y) * 128 + x] = sigm(zo) * tanh_fast(cn);
        }

        float* tmp = hout; hout = hpool; hpool = hprev; hprev = tmp;
    }

    // final pool2: pair (t=14, t=15) = (hpool, hprev), tp = 7
    gridbar(barcnt, 256, &phase);
    if (y < 2) {
        for (int e = tid; e < 48 * 8; e += 256) {
            int f = e >> 3, xl = e & 7;
            int xp = xq * 8 + xl;
            int g0 = ((b * 48 + f) * 4 + y * 2) * 128 + xp * 2;
            float m = fmaxf(fmaxf(hpool[g0], hpool[g0 + 1]),
                            fmaxf(hpool[g0 + 128], hpool[g0 + 129]));
            m = fmaxf(m, fmaxf(fmaxf(hprev[g0], hprev[g0 + 1]),
                               fmaxf(hprev[g0 + 128], hprev[g0 + 129])));
            int pi = ((b * 48 + f) * 16 + 7 * 2 + y) * 64 + xp;
            unsigned short hi = bf16_rne(m);
            p2hi[pi] = hi;
            p2lo[pi] = bf16_rne(m - bf16_to_f(hi));
        }
    }
}

// ---------------- conv3 (streaming MFMA, 3-term, K-split partials) ----------
__global__ __launch_bounds__(256) void conv3_part(
    const unsigned short* __restrict__ p2hi, const unsigned short* __restrict__ p2lo,
    const unsigned short* __restrict__ w3F,
    float* __restrict__ part)    // (12,256,112)
{
    __shared__ float sRed[4 * 7 * 256];
    const int mq = blockIdx.x, ck = blockIdx.y;
    const int tid = threadIdx.x;
    const int l = tid & 63;
    const int wv = __builtin_amdgcn_readfirstlane(tid >> 6);
    const int c = ck * 4 + wv;
    const int ln = l & 15, kg = l >> 4;

    int rowbase[7];
#pragma unroll
    for (int nt = 0; nt < 7; ++nt) {
        int col = nt * 16 + ln;
        int bi = col / 14, r = col % 14;
        rowbase[nt] = (bi * 48 + c) * 16 + r;
    }

    f32x4 acc[7];
#pragma unroll
    for (int nt = 0; nt < 7; ++nt) acc[nt] = (f32x4){0.f, 0.f, 0.f, 0.f};

#pragma unroll
    for (int kk = 0; kk < 6; ++kk) {
        int aoff = ((((mq * 48 + c) * 6 + kk) * 4 + kg) * 16 + ln) * 8;
        short8 ah = *(const short8*)&w3F[aoff];
        short8 al = *(const short8*)&w3F[PLANE_W3 + aoff];
        int s = kk * 4 + kg;
        int dr = s >> 3, w0 = (s & 7) * 8;
#pragma unroll
        for (int nt = 0; nt < 7; ++nt) {
            int boff = (rowbase[nt] + dr) * 64 + w0;
            short8 bh = *(const short8*)&p2hi[boff];
            short8 bl = *(const short8*)&p2lo[boff];
            acc[nt] = __builtin_amdgcn_mfma_f32_16x16x32_bf16(al, bh, acc[nt], 0, 0, 0);
            acc[nt] = __builtin_amdgcn_mfma_f32_16x16x32_bf16(ah, bl, acc[nt], 0, 0, 0);
            acc[nt] = __builtin_amdgcn_mfma_f32_16x16x32_bf16(ah, bh, acc[nt], 0, 0, 0);
        }
    }

#pragma unroll
    for (int nt = 0; nt < 7; ++nt)
        *(f32x4*)&sRed[wv * 1792 + nt * 256 + l * 4] = acc[nt];
    __syncthreads();

#pragma unroll
    for (int nt = 0; nt < 7; ++nt) {
        float s = sRed[nt * 256 + tid] + sRed[1792 + nt * 256 + tid] +
                  sRed[2 * 1792 + nt * 256 + tid] + sRed[3 * 1792 + nt * 256 + tid];
        int r16 = (tid >> 6) * 4 + (tid & 3);
        int m = mq * 16 + r16;
        int col = nt * 16 + ((tid >> 2) & 15);
        part[(ck * 256 + m) * 112 + col] = s;
    }
}

// ---------------- head: reduce+bias+ELU -> conv4+ELU -> conv5 ----------------
__global__ __launch_bounds__(256) void head(
    const float* __restrict__ part, const float* __restrict__ b3,
    const float* __restrict__ w4T, const float* __restrict__ b4,
    const float* __restrict__ w5T, const float* __restrict__ b5,
    float* __restrict__ out)
{
    __shared__ float sO3[256];
    __shared__ float sO4[128];
    const int col = blockIdx.x;          // b*14 + r
    const int b = col / 14, r = col % 14;
    const int tid = threadIdx.x;

    float s = b3[tid];
#pragma unroll
    for (int ck = 0; ck < 12; ++ck)
        s += part[(ck * 256 + tid) * 112 + col];
    sO3[tid] = elu(s);
    __syncthreads();

    if (tid < 128) {
        float a4 = b4[tid];
        for (int c = 0; c < 256; ++c)
            a4 = fmaf(sO3[c], w4T[c * 128 + tid], a4);
        sO4[tid] = elu(a4);
    }
    __syncthreads();

    if (tid < 88) {
        float a5 = b5[tid];
        for (int c = 0; c < 128; ++c)
            a5 = fmaf(sO4[c], w5T[c * 88 + tid], a5);
        out[(b * 88 + tid) * 14 + r] = a5;
    }
}

// ---------------- weight prepacks (8-wide fragments per thread) --------------
__global__ void prep(const float* __restrict__ w1, const float* __restrict__ w2,
                     const float* __restrict__ w3, const float* __restrict__ w4,
                     const float* __restrict__ w5,
                     unsigned short* __restrict__ w1F, unsigned short* __restrict__ w2F,
                     unsigned short* __restrict__ w3F,
                     float* __restrict__ w4T, float* __restrict__ w5T)
{
    int i = blockIdx.x * 256 + threadIdx.x;
    if (i < 6144) {            // w1F hi: [dx][mt 8][kk 4][kg 4][ln 16][8]
        int base = i * 8;
        int dx = base / 16384, rem = base % 16384;
        int mt = rem / 2048, r2 = rem % 2048;
        int kk = r2 / 512, r3 = r2 % 512;
        int kg = r3 / 128, ln = (r3 % 128) / 8;
        int f = mt * 4 + (ln >> 2), gate = ln & 3;
        int co = gate * 32 + f;
        int k0 = kk * 32 + kg * 8;
        short8 h;
#pragma unroll
        for (int e = 0; e < 8; ++e) {
            int k = k0 + e;
            float v = (k < 99) ? w1[co * 297 + (k / 3) * 9 + (k % 3) * 3 + dx] : 0.0f;
            h[e] = (short)bf16_rne(v);
        }
        *(short8*)&w1F[base] = h;
        return;
    }
    i -= 6144;
    if (i < 18432) {           // w2F hi: [dx][mt 12][kk 8][kg 4][ln 16][8]
        int base = i * 8;
        int dx = base / 49152, rem = base % 49152;
        int mt = rem / 4096, r2 = rem % 4096;
        int kk = r2 / 512, r3 = r2 % 512;
        int kg = r3 / 128, ln = (r3 % 128) / 8;
        int f = mt * 4 + (ln >> 2), gate = ln & 3;
        int co = gate * 48 + f;
        int k0 = kk * 32 + kg * 8;
        short8 h;
#pragma unroll
        for (int e = 0; e < 8; ++e) {
            int k = k0 + e;
            float v = (k < 240) ? w2[co * 720 + (k / 3) * 9 + (k % 3) * 3 + dx] : 0.0f;
            h[e] = (short)bf16_rne(v);
        }
        *(short8*)&w2F[base] = h;
        return;
    }
    i -= 18432;
    if (i < 294912) {          // w3F hi+lo: [mq 16][c 48][kk 6][kg 4][ln 16][8]
        int base = i * 8;
        int mq = base / 147456, rem = base % 147456;
        int c = rem / 3072, r2 = rem % 3072;
        int kk = r2 / 512, r3 = r2 % 512;
        int kg = r3 / 128, ln = (r3 % 128) / 8;
        int m = mq * 16 + ln;
        int kc0 = kk * 32 + kg * 8;
        int dr = kc0 >> 6, w0 = kc0 & 63;
        const float* src = &w3[((m * 48 + c) * 3 + dr) * 64 + w0];
        short8 hh, hl;
#pragma unroll
        for (int e = 0; e < 8; ++e) {
            float v = src[e];
            unsigned short hi = bf16_rne(v);
            hh[e] = (short)hi;
            hl[e] = (short)bf16_rne(v - bf16_to_f(hi));
        }
        *(short8*)&w3F[base] = hh;
        *(short8*)&w3F[PLANE_W3 + base] = hl;
        return;
    }
    i -= 294912;
    if (i < 32768) {           // w4 (128,256) -> w4T (256,128)
        int n = i / 256, cch = i % 256;
        w4T[cch * 128 + n] = w4[i];
        return;
    }
    i -= 32768;
    if (i < 11264) {           // w5 (88,128) -> w5T (128,88)
        int n = i / 128, cch = i % 128;
        w5T[cch * 88 + n] = w5[i];
    }
}

extern "C" void kernel_launch(void* const* d_in, const int* in_sizes, int n_in,
                              void* d_out, int out_size, void* d_ws, size_t ws_size,
                              hipStream_t stream)
{
    const float* x  = (const float*)d_in[0];
    const float* w1 = (const float*)d_in[1];
    const float* b1 = (const float*)d_in[2];
    const float* w2 = (const float*)d_in[3];
    const float* b2 = (const float*)d_in[4];
    const float* w3 = (const float*)d_in[5];
    const float* b3 = (const float*)d_in[6];
    const float* w4 = (const float*)d_in[7];
    const float* b4 = (const float*)d_in[8];
    const float* w5 = (const float*)d_in[9];
    const float* b5 = (const float*)d_in[10];
    float* out = (float*)d_out;

    float* ws = (float*)d_ws;
    size_t off = 0;
    auto alloc = [&](size_t n) { float* p = ws + off; off += n; return p; };
    float* h1a = alloc(524288);
    float* h1b = alloc(524288);
    float* h1c = alloc(524288);
    unsigned* p1pk = (unsigned*)alloc(2097152);             // (8,32,16,4,128) u32
    float* h2a = alloc(196608);
    float* h2b = alloc(196608);
    float* h2c = alloc(196608);
    unsigned short* p2hi = (unsigned short*)alloc(196608);  // 393216 u16
    unsigned short* p2lo = (unsigned short*)alloc(196608);
    float* part = alloc(344064);                            // (12,256,112)
    unsigned short* w1F = (unsigned short*)alloc(24576);    // 49152 u16 (hi)
    unsigned short* w2F = (unsigned short*)alloc(73728);    // 147456 u16 (hi)
    unsigned short* w3F = (unsigned short*)alloc(2359296);  // hi+lo planes
    float* w4T = alloc(32768);
    float* w5T = alloc(11264);
    unsigned* bar = (unsigned*)alloc(2);                    // barrier counters
    (void)ws_size; (void)off;

    hipMemsetAsync(h1c, 0, 524288 * sizeof(float), stream);
    hipMemsetAsync(h2c, 0, 196608 * sizeof(float), stream);
    hipMemsetAsync(bar, 0, 2 * sizeof(unsigned), stream);

    prep<<<1420, 256, 0, stream>>>(w1, w2, w3, w4, w5, w1F, w2F, w3F, w4T, w5T);

    // persistent LSTMs, regular launches; grid = 256 = #CUs, co-residency by
    // capacity (lstm1: <=256 VGPR -> 2 blocks/CU capacity; lstm2: 1 block/CU).
    lstm1_all<<<dim3(4, 8, 8), 512, 0, stream>>>(
        x, w1F, b1, h1a, h1b, h1c, p1pk, bar);
    lstm2_all<<<dim3(8, 4, 8), 256, 0, stream>>>(
        p1pk, w2F, b2, h2a, h2b, h2c, p2hi, p2lo, bar + 1);

    conv3_part<<<dim3(16, 12), 256, 0, stream>>>(p2hi, p2lo, w3F, part);
    head<<<112, 256, 0, stream>>>(part, b3, w4T, b4, w5T, b5, out);
}

// Round 9
// 641.233 us; speedup vs baseline: 2.4283x; 2.4283x over previous
//
#include <hip/hip_runtime.h>
#include <math.h>

// Net: ConvLSTM(32)->pool->ConvLSTM(48)->pool->conv3+ELU->conv4(1x1)+ELU->conv5(1x1)
// B=8, T=32, H=8, W=256, F1=32, F2=48, F3=256, F4=128, NNOTE=88
// R9: R6 structure (per-step launches; persistent+gridbar was 2.3x WORSE, R8).
//     h state stored packed bf16 hi|lo<<16 (u32) -> staging is unpack-only;
//     x pre-packed in prep. Numerics bit-identical to R6.

#define DEVINL static __device__ __forceinline__
typedef __attribute__((ext_vector_type(8))) short short8;
typedef __attribute__((ext_vector_type(4))) float f32x4;

#define PLANE_W3 2359296    // w3F (16*48*6*4*16*8), hi plane size (lo follows)

DEVINL float sigm(float x) { return 1.0f / (1.0f + __expf(-x)); }
DEVINL float tanh_fast(float x) { return 1.0f - 2.0f / (__expf(2.0f * x) + 1.0f); }
DEVINL float elu(float x) { return x > 0.0f ? x : expm1f(x); }
DEVINL unsigned short bf16_rne(float v) {
    unsigned u = __float_as_uint(v);
    unsigned r = (u + 0x7FFF + ((u >> 16) & 1)) >> 16;
    return (unsigned short)r;
}
DEVINL float bf16_to_f(unsigned short h) { return __uint_as_float(((unsigned)h) << 16); }
DEVINL unsigned pack_hl(float v) {
    unsigned short hi = bf16_rne(v);
    unsigned short lo = bf16_rne(v - bf16_to_f(hi));
    return (unsigned)hi | ((unsigned)lo << 16);
}
DEVINL float upk(unsigned u) {   // unpack hi+lo to float (3 VALU)
    return __uint_as_float(u << 16) + __uint_as_float(u & 0xffff0000u);
}

// ---------------- LSTM1 fused step (MFMA, 2-term split) ----------------
// grid (4,8,8) = (xq, y, b), block 512 = 8 waves = (mh 4) x (nh 2).
// h buffers PACKED u32 (hi|lo<<16). Pool of pair (t-2,t-1) fused at even t.
__global__ __launch_bounds__(512) void lstm1_step(
    const unsigned* __restrict__ xpk,        // (8,32,8,256) packed
    const unsigned short* __restrict__ w1F,  // hi only, [dx][mt][kk][kg][ln][8]
    const float* __restrict__ b1,            // (128)
    const unsigned* __restrict__ hprev,      // h1[(t+2)%3] packed
    const unsigned* __restrict__ hpool,      // h1[(t+1)%3] = t-2's h
    unsigned* __restrict__ hout,             // h1[t%3]
    float* __restrict__ c1,                  // (8,32,8,256) fp32
    unsigned* __restrict__ p1pk,             // (8,32,16,4,128) packed
    int t)
{
    __shared__ __align__(16) unsigned short sBhi[66 * 128];
    __shared__ __align__(16) unsigned short sBlo[66 * 128];
    const int xq = blockIdx.x, y = blockIdx.y, b = blockIdx.z;
    const int x0 = xq * 64;
    const int tid = threadIdx.x;

    // fused pool of pair (t-2, t-1) -> p1[tp], odd-y blocks
    if (((t & 1) == 0) && t >= 2 && (y & 1) == 1) {
        int tp = (t >> 1) - 1, yp = y >> 1;
        for (int e = tid; e < 1024; e += 512) {
            int f = e >> 5, xl = e & 31;
            int xp = (x0 >> 1) + xl, gx = x0 + 2 * xl;
            int b0 = ((b * 32 + f) * 8 + (y - 1)) * 256 + gx;
            float m = upk(hpool[b0]);
            m = fmaxf(m, upk(hpool[b0 + 1]));
            m = fmaxf(m, upk(hpool[b0 + 256]));
            m = fmaxf(m, upk(hpool[b0 + 257]));
            m = fmaxf(m, upk(hprev[b0]));
            m = fmaxf(m, upk(hprev[b0 + 1]));
            m = fmaxf(m, upk(hprev[b0 + 256]));
            m = fmaxf(m, upk(hprev[b0 + 257]));
            p1pk[(((b * 32 + f) * 16 + tp) * 4 + yp) * 128 + xp] = pack_hl(m);
        }
    }

    // stage input tile: load packed u32, split into hi/lo planes (swizzled)
    for (int e = tid; e < 66 * 128; e += 512) {
        int lx = e % 66, kk = e / 66;
        unsigned u = 0;
        if (kk < 99) {
            int ci = kk / 3, dy = kk - ci * 3;
            int gy = y + dy - 1, gx = x0 + lx - 1;
            if (gy >= 0 && gy < 8 && gx >= 0 && gx < 256)
                u = (ci == 0) ? xpk[((b * 32 + t) * 8 + gy) * 256 + gx]
                              : hprev[((b * 32 + (ci - 1)) * 8 + gy) * 256 + gx];
        }
        int a16 = lx * 128 + (((kk >> 3) ^ (lx & 15)) << 3) + (kk & 7);
        sBhi[a16] = (unsigned short)u;
        sBlo[a16] = (unsigned short)(u >> 16);
    }
    __syncthreads();

    const int l = tid & 63;
    const int wv = __builtin_amdgcn_readfirstlane(tid >> 6);
    const int mh = wv >> 1, nh = wv & 1;
    const int ln = l & 15, kg = l >> 4;
    f32x4 acc[2][2];
#pragma unroll
    for (int i = 0; i < 2; ++i)
#pragma unroll
        for (int j = 0; j < 2; ++j) acc[i][j] = (f32x4){0.f, 0.f, 0.f, 0.f};

#pragma unroll
    for (int kk = 0; kk < 4; ++kk) {
        short8 bh[2][3], bl[2][3];
#pragma unroll
        for (int ntl = 0; ntl < 2; ++ntl)
#pragma unroll
            for (int dx = 0; dx < 3; ++dx) {
                int lx = (nh * 2 + ntl) * 16 + ln + dx;
                int slot = kk * 4 + kg;
                int boff = lx * 128 + ((slot ^ (lx & 15)) << 3);
                bh[ntl][dx] = *(const short8*)&sBhi[boff];
                bl[ntl][dx] = *(const short8*)&sBlo[boff];
            }
#pragma unroll
        for (int mtl = 0; mtl < 2; ++mtl)
#pragma unroll
            for (int dx = 0; dx < 3; ++dx) {
                int aoff = ((((dx * 8 + mh * 2 + mtl) * 4 + kk) * 4 + kg) * 16 + ln) * 8;
                short8 ah = *(const short8*)&w1F[aoff];
#pragma unroll
                for (int ntl = 0; ntl < 2; ++ntl) {
                    acc[mtl][ntl] = __builtin_amdgcn_mfma_f32_16x16x32_bf16(ah, bl[ntl][dx], acc[mtl][ntl], 0, 0, 0);
                    acc[mtl][ntl] = __builtin_amdgcn_mfma_f32_16x16x32_bf16(ah, bh[ntl][dx], acc[mtl][ntl], 0, 0, 0);
                }
            }
    }

#pragma unroll
    for (int mtl = 0; mtl < 2; ++mtl) {
        const int f = (mh * 2 + mtl) * 4 + kg;
        const float bi = b1[f], bff = b1[32 + f], bg = b1[64 + f], bo = b1[96 + f];
#pragma unroll
        for (int ntl = 0; ntl < 2; ++ntl) {
            f32x4 a = acc[mtl][ntl];
            int gidx = ((b * 32 + f) * 8 + y) * 256 + x0 + (nh * 2 + ntl) * 16 + ln;
            float zi = a[0] + bi, zf = a[1] + bff, zg = a[2] + bg, zo = a[3] + bo;
            float cv = c1[gidx];
            float cn = sigm(zf) * cv + sigm(zi) * tanh_fast(zg);
            c1[gidx] = cn;
            hout[gidx] = pack_hl(sigm(zo) * tanh_fast(cn));
        }
    }
}

// ---------------- final pool1 for tp=15 ----------------
__global__ void pool1k(const unsigned* __restrict__ hA, const unsigned* __restrict__ hB,
                       unsigned* __restrict__ p1pk, int tp)
{
    int idx = blockIdx.x * 256 + threadIdx.x;
    if (idx >= 8 * 32 * 4 * 128) return;
    int xp = idx & 127, t1 = idx >> 7;
    int yp = t1 & 3, t2 = t1 >> 2;
    int f = t2 & 31, b = t2 >> 5;
    int base = ((b * 32 + f) * 8 + yp * 2) * 256 + xp * 2;
    float m = upk(hA[base]);
    m = fmaxf(m, upk(hA[base + 1]));
    m = fmaxf(m, upk(hA[base + 256]));
    m = fmaxf(m, upk(hA[base + 257]));
    m = fmaxf(m, upk(hB[base]));
    m = fmaxf(m, upk(hB[base + 1]));
    m = fmaxf(m, upk(hB[base + 256]));
    m = fmaxf(m, upk(hB[base + 257]));
    p1pk[(((b * 32 + f) * 16 + tp) * 4 + yp) * 128 + xp] = pack_hl(m);
}

// ---------------- LSTM2 step (MFMA, 2-term, gates + prev-pair pool fused) ----
// grid (8,4,8) = (xq, y, b), block 256 = 4 waves; wave wv owns mt = wv*3..wv*3+2.
__global__ __launch_bounds__(256) void lstm2_step(
    const unsigned* __restrict__ p1pk,
    const unsigned short* __restrict__ w2F,  // hi only, [dx][mt][kk][kg][ln][8]
    const float* __restrict__ b2,            // (192)
    const unsigned* __restrict__ hprev,      // h2[(t+2)%3] packed
    const unsigned* __restrict__ hpool,      // h2[(t+1)%3] = t-2's h
    float* __restrict__ c2,                  // (8,48,4,128) fp32
    unsigned* __restrict__ hout,             // h2[t%3]
    unsigned short* __restrict__ p2hi, unsigned short* __restrict__ p2lo,
    int t)
{
    __shared__ __align__(16) unsigned short sBhi[18 * 256];
    __shared__ __align__(16) unsigned short sBlo[18 * 256];
    const int xq = blockIdx.x, y = blockIdx.y, b = blockIdx.z;
    const int x0 = xq * 16;
    const int tid = threadIdx.x;

    if (((t & 1) == 0) && t >= 2 && y < 2) {
        int tp = (t >> 1) - 1;
        for (int e = tid; e < 48 * 8; e += 256) {
            int f = e >> 3, xl = e & 7;
            int xp = xq * 8 + xl;
            int g0 = ((b * 48 + f) * 4 + y * 2) * 128 + xp * 2;
            float m = fmaxf(fmaxf(upk(hpool[g0]), upk(hpool[g0 + 1])),
                            fmaxf(upk(hpool[g0 + 128]), upk(hpool[g0 + 129])));
            m = fmaxf(m, fmaxf(fmaxf(upk(hprev[g0]), upk(hprev[g0 + 1])),
                               fmaxf(upk(hprev[g0 + 128]), upk(hprev[g0 + 129]))));
            int pi = ((b * 48 + f) * 16 + tp * 2 + y) * 64 + xp;
            unsigned pm = pack_hl(m);
            p2hi[pi] = (unsigned short)pm;
            p2lo[pi] = (unsigned short)(pm >> 16);
        }
    }

    for (int idx = tid; idx < 80 * 54; idx += 256) {
        int ci = idx / 54, rem = idx % 54;
        int dy = rem / 18, lx = rem % 18;
        int gy = y + dy - 1, gx = x0 + lx - 1;
        unsigned u = 0;
        if (gy >= 0 && gy < 4 && gx >= 0 && gx < 128)
            u = (ci < 32) ? p1pk[(((b * 32 + ci) * 16 + t) * 4 + gy) * 128 + gx]
                          : hprev[((b * 48 + (ci - 32)) * 4 + gy) * 128 + gx];
        int k = ci * 3 + dy;
        int a16 = lx * 256 + (((k >> 3) ^ (lx & 15)) << 3) + (k & 7);
        sBhi[a16] = (unsigned short)u;
        sBlo[a16] = (unsigned short)(u >> 16);
    }
    // zero pad slots (k = 240..255)
    for (int e = tid; e < 18 * 16; e += 256) {
        int lx = e >> 4, k = 240 + (e & 15);
        int a16 = lx * 256 + (((k >> 3) ^ (lx & 15)) << 3) + (k & 7);
        sBhi[a16] = 0;
        sBlo[a16] = 0;
    }
    __syncthreads();

    const int l = tid & 63;
    const int wv = __builtin_amdgcn_readfirstlane(tid >> 6);
    const int ln = l & 15, kg = l >> 4;
    f32x4 acc[3] = {{0.f,0.f,0.f,0.f},{0.f,0.f,0.f,0.f},{0.f,0.f,0.f,0.f}};

#pragma unroll
    for (int kk = 0; kk < 8; ++kk) {
        short8 bh[3], bl[3];
#pragma unroll
        for (int dx = 0; dx < 3; ++dx) {
            int lx = ln + dx;
            int boff = lx * 256 + ((((kk << 2) + kg) ^ (lx & 15)) << 3);
            bh[dx] = *(const short8*)&sBhi[boff];
            bl[dx] = *(const short8*)&sBlo[boff];
        }
#pragma unroll
        for (int j = 0; j < 3; ++j) {
            int mt = wv * 3 + j;
#pragma unroll
            for (int dx = 0; dx < 3; ++dx) {
                int aoff = ((((dx * 12 + mt) * 8 + kk) * 4 + kg) * 16 + ln) * 8;
                short8 ah = *(const short8*)&w2F[aoff];
                acc[j] = __builtin_amdgcn_mfma_f32_16x16x32_bf16(ah, bl[dx], acc[j], 0, 0, 0);
                acc[j] = __builtin_amdgcn_mfma_f32_16x16x32_bf16(ah, bh[dx], acc[j], 0, 0, 0);
            }
        }
    }

    const int x = x0 + ln;
#pragma unroll
    for (int j = 0; j < 3; ++j) {
        int mt = wv * 3 + j;
        int f = mt * 4 + kg;
        float zi = acc[j][0] + b2[f];
        float zf = acc[j][1] + b2[48 + f];
        float zg = acc[j][2] + b2[96 + f];
        float zo = acc[j][3] + b2[144 + f];
        int gidx = ((b * 48 + f) * 4 + y) * 128 + x;
        float cv = c2[gidx];
        float cn = sigm(zf) * cv + sigm(zi) * tanh_fast(zg);
        c2[gidx] = cn;
        hout[gidx] = pack_hl(sigm(zo) * tanh_fast(cn));
    }
}

// ---------------- final pool2 for tp=7 ----------------
__global__ void pool2(const unsigned* __restrict__ hA, const unsigned* __restrict__ hB,
                      unsigned short* __restrict__ p2hi, unsigned short* __restrict__ p2lo,
                      int tp)
{
    int idx = blockIdx.x * 256 + threadIdx.x;
    if (idx >= 8 * 48 * 2 * 64) return;
    int xp = idx & 63;
    int t1 = idx >> 6;
    int yp = t1 & 1; t1 >>= 1;
    int f = t1 % 48, b = t1 / 48;
    float m = -INFINITY;
#pragma unroll
    for (int dy = 0; dy < 2; ++dy)
#pragma unroll
        for (int dx = 0; dx < 2; ++dx) {
            int g = ((b * 48 + f) * 4 + yp * 2 + dy) * 128 + xp * 2 + dx;
            m = fmaxf(m, fmaxf(upk(hA[g]), upk(hB[g])));
        }
    int pi = ((b * 48 + f) * 16 + tp * 2 + yp) * 64 + xp;
    unsigned pm = pack_hl(m);
    p2hi[pi] = (unsigned short)pm;
    p2lo[pi] = (unsigned short)(pm >> 16);
}

// ---------------- conv3 (streaming MFMA, 3-term, K-split partials) ----------
__global__ __launch_bounds__(256) void conv3_part(
    const unsigned short* __restrict__ p2hi, const unsigned short* __restrict__ p2lo,
    const unsigned short* __restrict__ w3F,
    float* __restrict__ part)    // (12,256,112)
{
    __shared__ float sRed[4 * 7 * 256];
    const int mq = blockIdx.x, ck = blockIdx.y;
    const int tid = threadIdx.x;
    const int l = tid & 63;
    const int wv = __builtin_amdgcn_readfirstlane(tid >> 6);
    const int c = ck * 4 + wv;
    const int ln = l & 15, kg = l >> 4;

    int rowbase[7];
#pragma unroll
    for (int nt = 0; nt < 7; ++nt) {
        int col = nt * 16 + ln;
        int bi = col / 14, r = col % 14;
        rowbase[nt] = (bi * 48 + c) * 16 + r;
    }

    f32x4 acc[7];
#pragma unroll
    for (int nt = 0; nt < 7; ++nt) acc[nt] = (f32x4){0.f, 0.f, 0.f, 0.f};

#pragma unroll
    for (int kk = 0; kk < 6; ++kk) {
        int aoff = ((((mq * 48 + c) * 6 + kk) * 4 + kg) * 16 + ln) * 8;
        short8 ah = *(const short8*)&w3F[aoff];
        short8 al = *(const short8*)&w3F[PLANE_W3 + aoff];
        int s = kk * 4 + kg;
        int dr = s >> 3, w0 = (s & 7) * 8;
#pragma unroll
        for (int nt = 0; nt < 7; ++nt) {
            int boff = (rowbase[nt] + dr) * 64 + w0;
            short8 bh = *(const short8*)&p2hi[boff];
            short8 bl = *(const short8*)&p2lo[boff];
            acc[nt] = __builtin_amdgcn_mfma_f32_16x16x32_bf16(al, bh, acc[nt], 0, 0, 0);
            acc[nt] = __builtin_amdgcn_mfma_f32_16x16x32_bf16(ah, bl, acc[nt], 0, 0, 0);
            acc[nt] = __builtin_amdgcn_mfma_f32_16x16x32_bf16(ah, bh, acc[nt], 0, 0, 0);
        }
    }

#pragma unroll
    for (int nt = 0; nt < 7; ++nt)
        *(f32x4*)&sRed[wv * 1792 + nt * 256 + l * 4] = acc[nt];
    __syncthreads();

#pragma unroll
    for (int nt = 0; nt < 7; ++nt) {
        float s = sRed[nt * 256 + tid] + sRed[1792 + nt * 256 + tid] +
                  sRed[2 * 1792 + nt * 256 + tid] + sRed[3 * 1792 + nt * 256 + tid];
        int r16 = (tid >> 6) * 4 + (tid & 3);
        int m = mq * 16 + r16;
        int col = nt * 16 + ((tid >> 2) & 15);
        part[(ck * 256 + m) * 112 + col] = s;
    }
}

// ---------------- head: reduce+bias+ELU -> conv4+ELU -> conv5 ----------------
__global__ __launch_bounds__(256) void head(
    const float* __restrict__ part, const float* __restrict__ b3,
    const float* __restrict__ w4T, const float* __restrict__ b4,
    const float* __restrict__ w5T, const float* __restrict__ b5,
    float* __restrict__ out)
{
    __shared__ float sO3[256];
    __shared__ float sO4[128];
    const int col = blockIdx.x;          // b*14 + r
    const int b = col / 14, r = col % 14;
    const int tid = threadIdx.x;

    float s = b3[tid];
#pragma unroll
    for (int ck = 0; ck < 12; ++ck)
        s += part[(ck * 256 + tid) * 112 + col];
    sO3[tid] = elu(s);
    __syncthreads();

    if (tid < 128) {
        float a4 = b4[tid];
        for (int c = 0; c < 256; ++c)
            a4 = fmaf(sO3[c], w4T[c * 128 + tid], a4);
        sO4[tid] = elu(a4);
    }
    __syncthreads();

    if (tid < 88) {
        float a5 = b5[tid];
        for (int c = 0; c < 128; ++c)
            a5 = fmaf(sO4[c], w5T[c * 88 + tid], a5);
        out[(b * 88 + tid) * 14 + r] = a5;
    }
}

// ---------------- prep: x pack + weight prepacks ----------------
__global__ void prep(const float* __restrict__ x, const float* __restrict__ w1,
                     const float* __restrict__ w2, const float* __restrict__ w3,
                     const float* __restrict__ w4, const float* __restrict__ w5,
                     unsigned* __restrict__ xpk,
                     unsigned short* __restrict__ w1F, unsigned short* __restrict__ w2F,
                     unsigned short* __restrict__ w3F,
                     float* __restrict__ w4T, float* __restrict__ w5T)
{
    int i = blockIdx.x * 256 + threadIdx.x;
    if (i < 131072) {          // x -> packed u32, 4 per thread
        const float4 v = *(const float4*)&x[i * 4];
        uint4 o;
        o.x = pack_hl(v.x); o.y = pack_hl(v.y);
        o.z = pack_hl(v.z); o.w = pack_hl(v.w);
        *(uint4*)&xpk[i * 4] = o;
        return;
    }
    i -= 131072;
    if (i < 6144) {            // w1F hi: [dx][mt 8][kk 4][kg 4][ln 16][8]
        int base = i * 8;
        int dx = base / 16384, rem = base % 16384;
        int mt = rem / 2048, r2 = rem % 2048;
        int kk = r2 / 512, r3 = r2 % 512;
        int kg = r3 / 128, ln = (r3 % 128) / 8;
        int f = mt * 4 + (ln >> 2), gate = ln & 3;
        int co = gate * 32 + f;
        int k0 = kk * 32 + kg * 8;
        short8 h;
#pragma unroll
        for (int e = 0; e < 8; ++e) {
            int k = k0 + e;
            float v = (k < 99) ? w1[co * 297 + (k / 3) * 9 + (k % 3) * 3 + dx] : 0.0f;
            h[e] = (short)bf16_rne(v);
        }
        *(short8*)&w1F[base] = h;
        return;
    }
    i -= 6144;
    if (i < 18432) {           // w2F hi: [dx][mt 12][kk 8][kg 4][ln 16][8]
        int base = i * 8;
        int dx = base / 49152, rem = base % 49152;
        int mt = rem / 4096, r2 = rem % 4096;
        int kk = r2 / 512, r3 = r2 % 512;
        int kg = r3 / 128, ln = (r3 % 128) / 8;
        int f = mt * 4 + (ln >> 2), gate = ln & 3;
        int co = gate * 48 + f;
        int k0 = kk * 32 + kg * 8;
        short8 h;
#pragma unroll
        for (int e = 0; e < 8; ++e) {
            int k = k0 + e;
            float v = (k < 240) ? w2[co * 720 + (k / 3) * 9 + (k % 3) * 3 + dx] : 0.0f;
            h[e] = (short)bf16_rne(v);
        }
        *(short8*)&w2F[base] = h;
        return;
    }
    i -= 18432;
    if (i < 294912) {          // w3F hi+lo: [mq 16][c 48][kk 6][kg 4][ln 16][8]
        int base = i * 8;
        int mq = base / 147456, rem = base % 147456;
        int c = rem / 3072, r2 = rem % 3072;
        int kk = r2 / 512, r3 = r2 % 512;
        int kg = r3 / 128, ln = (r3 % 128) / 8;
        int m = mq * 16 + ln;
        int kc0 = kk * 32 + kg * 8;
        int dr = kc0 >> 6, w0 = kc0 & 63;
        const float* src = &w3[((m * 48 + c) * 3 + dr) * 64 + w0];
        short8 hh, hl;
#pragma unroll
        for (int e = 0; e < 8; ++e) {
            float v = src[e];
            unsigned short hi = bf16_rne(v);
            hh[e] = (short)hi;
            hl[e] = (short)bf16_rne(v - bf16_to_f(hi));
        }
        *(short8*)&w3F[base] = hh;
        *(short8*)&w3F[PLANE_W3 + base] = hl;
        return;
    }
    i -= 294912;
    if (i < 32768) {           // w4 (128,256) -> w4T (256,128)
        int n = i / 256, cch = i % 256;
        w4T[cch * 128 + n] = w4[i];
        return;
    }
    i -= 32768;
    if (i < 11264) {           // w5 (88,128) -> w5T (128,88)
        int n = i / 128, cch = i % 128;
        w5T[cch * 88 + n] = w5[i];
    }
}

extern "C" void kernel_launch(void* const* d_in, const int* in_sizes, int n_in,
                              void* d_out, int out_size, void* d_ws, size_t ws_size,
                              hipStream_t stream)
{
    const float* x  = (const float*)d_in[0];
    const float* w1 = (const float*)d_in[1];
    const float* b1 = (const float*)d_in[2];
    const float* w2 = (const float*)d_in[3];
    const float* b2 = (const float*)d_in[4];
    const float* w3 = (const float*)d_in[5];
    const float* b3 = (const float*)d_in[6];
    const float* w4 = (const float*)d_in[7];
    const float* b4 = (const float*)d_in[8];
    const float* w5 = (const float*)d_in[9];
    const float* b5 = (const float*)d_in[10];
    float* out = (float*)d_out;

    float* ws = (float*)d_ws;
    size_t off = 0;
    auto alloc = [&](size_t n) { float* p = ws + off; off += n; return p; };
    unsigned* h1[3];
    h1[0] = (unsigned*)alloc(524288); h1[1] = (unsigned*)alloc(524288);
    h1[2] = (unsigned*)alloc(524288);
    float* c1 = alloc(524288);
    unsigned* xpk = (unsigned*)alloc(524288);               // (8,32,8,256) packed
    unsigned* p1pk = (unsigned*)alloc(2097152);             // (8,32,16,4,128) u32
    unsigned* h2[3];
    h2[0] = (unsigned*)alloc(196608); h2[1] = (unsigned*)alloc(196608);
    h2[2] = (unsigned*)alloc(196608);
    float* c2 = alloc(196608);
    unsigned short* p2hi = (unsigned short*)alloc(196608);  // 393216 u16
    unsigned short* p2lo = (unsigned short*)alloc(196608);
    float* part = alloc(344064);                            // (12,256,112)
    unsigned short* w1F = (unsigned short*)alloc(24576);    // 49152 u16 (hi)
    unsigned short* w2F = (unsigned short*)alloc(73728);    // 147456 u16 (hi)
    unsigned short* w3F = (unsigned short*)alloc(2359296);  // hi+lo planes
    float* w4T = alloc(32768);
    float* w5T = alloc(11264);
    (void)ws_size; (void)off;  // ~35 MB total

    hipMemsetAsync(h1[2], 0, 524288 * sizeof(unsigned), stream);
    hipMemsetAsync(c1,    0, 524288 * sizeof(float), stream);
    hipMemsetAsync(h2[2], 0, 196608 * sizeof(unsigned), stream);
    hipMemsetAsync(c2,    0, 196608 * sizeof(float), stream);

    prep<<<1932, 256, 0, stream>>>(x, w1, w2, w3, w4, w5, xpk,
                                   w1F, w2F, w3F, w4T, w5T);

    for (int t = 0; t < 32; ++t) {
        lstm1_step<<<dim3(4, 8, 8), 512, 0, stream>>>(
            xpk, w1F, b1, h1[(t + 2) % 3], h1[(t + 1) % 3], h1[t % 3], c1,
            p1pk, t);
    }
    pool1k<<<512, 256, 0, stream>>>(h1[0], h1[1], p1pk, 15); // t=30,31

    for (int t = 0; t < 16; ++t) {
        lstm2_step<<<dim3(8, 4, 8), 256, 0, stream>>>(
            p1pk, w2F, b2, h2[(t + 2) % 3], h2[(t + 1) % 3], c2, h2[t % 3],
            p2hi, p2lo, t);
    }
    pool2<<<192, 256, 0, stream>>>(h2[2], h2[0], p2hi, p2lo, 7);   // t=14,15

    conv3_part<<<dim3(16, 12), 256, 0, stream>>>(p2hi, p2lo, w3F, part);
    head<<<112, 256, 0, stream>>>(part, b3, w4T, b4, w5T, b5, out);
}

// Round 10
// 634.499 us; speedup vs baseline: 2.4541x; 1.0106x over previous
//
#include <hip/hip_runtime.h>
#include <math.h>

// Net: ConvLSTM(32)->pool->ConvLSTM(48)->pool->conv3+ELU->conv4(1x1)+ELU->conv5(1x1)
// B=8, T=32, H=8, W=256, F1=32, F2=48, F3=256, F4=128, NNOTE=88
// R10: lstm1 re-tiled to 512 blocks x 256 thr (32-wide x-tiles) -> 2 blocks/CU;
//      one block's MFMA overlaps the other's staging/barrier. Per-wave work and
//      numerics identical to R9.

#define DEVINL static __device__ __forceinline__
typedef __attribute__((ext_vector_type(8))) short short8;
typedef __attribute__((ext_vector_type(4))) float f32x4;

#define PLANE_W3 2359296    // w3F (16*48*6*4*16*8), hi plane size (lo follows)

DEVINL float sigm(float x) { return 1.0f / (1.0f + __expf(-x)); }
DEVINL float tanh_fast(float x) { return 1.0f - 2.0f / (__expf(2.0f * x) + 1.0f); }
DEVINL float elu(float x) { return x > 0.0f ? x : expm1f(x); }
DEVINL unsigned short bf16_rne(float v) {
    unsigned u = __float_as_uint(v);
    unsigned r = (u + 0x7FFF + ((u >> 16) & 1)) >> 16;
    return (unsigned short)r;
}
DEVINL float bf16_to_f(unsigned short h) { return __uint_as_float(((unsigned)h) << 16); }
DEVINL unsigned pack_hl(float v) {
    unsigned short hi = bf16_rne(v);
    unsigned short lo = bf16_rne(v - bf16_to_f(hi));
    return (unsigned)hi | ((unsigned)lo << 16);
}
DEVINL float upk(unsigned u) {
    return __uint_as_float(u << 16) + __uint_as_float(u & 0xffff0000u);
}

// ---------------- LSTM1 fused step (MFMA, 2-term split) ----------------
// grid (8,8,8) = (xq, y, b), block 256 = 4 waves; 2 blocks/CU for phase overlap.
// Wave wv: M-tiles {wv*2, wv*2+1} x N-tiles {0,1} of the 32-wide x-tile.
// C/D: col=lane&15, row=kg*4+reg -> lane holds gates i/f/g/o of f = mt*4+kg.
__global__ __launch_bounds__(256) void lstm1_step(
    const unsigned* __restrict__ xpk,        // (8,32,8,256) packed
    const unsigned short* __restrict__ w1F,  // hi only, [dx][mt][kk][kg][ln][8]
    const float* __restrict__ b1,            // (128)
    const unsigned* __restrict__ hprev,      // h1[(t+2)%3] packed
    const unsigned* __restrict__ hpool,      // h1[(t+1)%3] = t-2's h
    unsigned* __restrict__ hout,             // h1[t%3]
    float* __restrict__ c1,                  // (8,32,8,256) fp32
    unsigned* __restrict__ p1pk,             // (8,32,16,4,128) packed
    int t)
{
    __shared__ __align__(16) unsigned short sBhi[34 * 128];
    __shared__ __align__(16) unsigned short sBlo[34 * 128];
    const int xq = blockIdx.x, y = blockIdx.y, b = blockIdx.z;
    const int x0 = xq * 32;
    const int tid = threadIdx.x;

    // fused pool of pair (t-2, t-1) -> p1[tp], odd-y blocks (16 xp each)
    if (((t & 1) == 0) && t >= 2 && (y & 1) == 1) {
        int tp = (t >> 1) - 1, yp = y >> 1;
        for (int e = tid; e < 512; e += 256) {
            int f = e >> 4, xl = e & 15;
            int xp = (x0 >> 1) + xl, gx = x0 + 2 * xl;
            int b0 = ((b * 32 + f) * 8 + (y - 1)) * 256 + gx;
            float m = upk(hpool[b0]);
            m = fmaxf(m, upk(hpool[b0 + 1]));
            m = fmaxf(m, upk(hpool[b0 + 256]));
            m = fmaxf(m, upk(hpool[b0 + 257]));
            m = fmaxf(m, upk(hprev[b0]));
            m = fmaxf(m, upk(hprev[b0 + 1]));
            m = fmaxf(m, upk(hprev[b0 + 256]));
            m = fmaxf(m, upk(hprev[b0 + 257]));
            p1pk[(((b * 32 + f) * 16 + tp) * 4 + yp) * 128 + xp] = pack_hl(m);
        }
    }

    // stage input tile: load packed u32, split into hi/lo planes (swizzled)
    for (int e = tid; e < 34 * 128; e += 256) {
        int lx = e % 34, kk = e / 34;
        unsigned u = 0;
        if (kk < 99) {
            int ci = kk / 3, dy = kk - ci * 3;
            int gy = y + dy - 1, gx = x0 + lx - 1;
            if (gy >= 0 && gy < 8 && gx >= 0 && gx < 256)
                u = (ci == 0) ? xpk[((b * 32 + t) * 8 + gy) * 256 + gx]
                              : hprev[((b * 32 + (ci - 1)) * 8 + gy) * 256 + gx];
        }
        int a16 = lx * 128 + (((kk >> 3) ^ (lx & 15)) << 3) + (kk & 7);
        sBhi[a16] = (unsigned short)u;
        sBlo[a16] = (unsigned short)(u >> 16);
    }
    __syncthreads();

    const int l = tid & 63;
    const int wv = __builtin_amdgcn_readfirstlane(tid >> 6); // 0..3
    const int ln = l & 15, kg = l >> 4;
    f32x4 acc[2][2];
#pragma unroll
    for (int i = 0; i < 2; ++i)
#pragma unroll
        for (int j = 0; j < 2; ++j) acc[i][j] = (f32x4){0.f, 0.f, 0.f, 0.f};

#pragma unroll
    for (int kk = 0; kk < 4; ++kk) {
        short8 bh[2][3], bl[2][3];
#pragma unroll
        for (int ntl = 0; ntl < 2; ++ntl)
#pragma unroll
            for (int dx = 0; dx < 3; ++dx) {
                int lx = ntl * 16 + ln + dx;
                int slot = kk * 4 + kg;
                int boff = lx * 128 + ((slot ^ (lx & 15)) << 3);
                bh[ntl][dx] = *(const short8*)&sBhi[boff];
                bl[ntl][dx] = *(const short8*)&sBlo[boff];
            }
#pragma unroll
        for (int mtl = 0; mtl < 2; ++mtl)
#pragma unroll
            for (int dx = 0; dx < 3; ++dx) {
                int aoff = ((((dx * 8 + wv * 2 + mtl) * 4 + kk) * 4 + kg) * 16 + ln) * 8;
                short8 ah = *(const short8*)&w1F[aoff];
#pragma unroll
                for (int ntl = 0; ntl < 2; ++ntl) {
                    acc[mtl][ntl] = __builtin_amdgcn_mfma_f32_16x16x32_bf16(ah, bl[ntl][dx], acc[mtl][ntl], 0, 0, 0);
                    acc[mtl][ntl] = __builtin_amdgcn_mfma_f32_16x16x32_bf16(ah, bh[ntl][dx], acc[mtl][ntl], 0, 0, 0);
                }
            }
    }

#pragma unroll
    for (int mtl = 0; mtl < 2; ++mtl) {
        const int f = (wv * 2 + mtl) * 4 + kg;
        const float bi = b1[f], bff = b1[32 + f], bg = b1[64 + f], bo = b1[96 + f];
#pragma unroll
        for (int ntl = 0; ntl < 2; ++ntl) {
            f32x4 a = acc[mtl][ntl];
            int gidx = ((b * 32 + f) * 8 + y) * 256 + x0 + ntl * 16 + ln;
            float zi = a[0] + bi, zf = a[1] + bff, zg = a[2] + bg, zo = a[3] + bo;
            float cv = c1[gidx];
            float cn = sigm(zf) * cv + sigm(zi) * tanh_fast(zg);
            c1[gidx] = cn;
            hout[gidx] = pack_hl(sigm(zo) * tanh_fast(cn));
        }
    }
}

// ---------------- final pool1 for tp=15 ----------------
__global__ void pool1k(const unsigned* __restrict__ hA, const unsigned* __restrict__ hB,
                       unsigned* __restrict__ p1pk, int tp)
{
    int idx = blockIdx.x * 256 + threadIdx.x;
    if (idx >= 8 * 32 * 4 * 128) return;
    int xp = idx & 127, t1 = idx >> 7;
    int yp = t1 & 3, t2 = t1 >> 2;
    int f = t2 & 31, b = t2 >> 5;
    int base = ((b * 32 + f) * 8 + yp * 2) * 256 + xp * 2;
    float m = upk(hA[base]);
    m = fmaxf(m, upk(hA[base + 1]));
    m = fmaxf(m, upk(hA[base + 256]));
    m = fmaxf(m, upk(hA[base + 257]));
    m = fmaxf(m, upk(hB[base]));
    m = fmaxf(m, upk(hB[base + 1]));
    m = fmaxf(m, upk(hB[base + 256]));
    m = fmaxf(m, upk(hB[base + 257]));
    p1pk[(((b * 32 + f) * 16 + tp) * 4 + yp) * 128 + xp] = pack_hl(m);
}

// ---------------- LSTM2 step (MFMA, 2-term, gates + prev-pair pool fused) ----
// grid (8,4,8) = (xq, y, b), block 256 = 4 waves; wave wv owns mt = wv*3..wv*3+2.
__global__ __launch_bounds__(256) void lstm2_step(
    const unsigned* __restrict__ p1pk,
    const unsigned short* __restrict__ w2F,  // hi only, [dx][mt][kk][kg][ln][8]
    const float* __restrict__ b2,            // (192)
    const unsigned* __restrict__ hprev,      // h2[(t+2)%3] packed
    const unsigned* __restrict__ hpool,      // h2[(t+1)%3] = t-2's h
    float* __restrict__ c2,                  // (8,48,4,128) fp32
    unsigned* __restrict__ hout,             // h2[t%3]
    unsigned short* __restrict__ p2hi, unsigned short* __restrict__ p2lo,
    int t)
{
    __shared__ __align__(16) unsigned short sBhi[18 * 256];
    __shared__ __align__(16) unsigned short sBlo[18 * 256];
    const int xq = blockIdx.x, y = blockIdx.y, b = blockIdx.z;
    const int x0 = xq * 16;
    const int tid = threadIdx.x;

    if (((t & 1) == 0) && t >= 2 && y < 2) {
        int tp = (t >> 1) - 1;
        for (int e = tid; e < 48 * 8; e += 256) {
            int f = e >> 3, xl = e & 7;
            int xp = xq * 8 + xl;
            int g0 = ((b * 48 + f) * 4 + y * 2) * 128 + xp * 2;
            float m = fmaxf(fmaxf(upk(hpool[g0]), upk(hpool[g0 + 1])),
                            fmaxf(upk(hpool[g0 + 128]), upk(hpool[g0 + 129])));
            m = fmaxf(m, fmaxf(fmaxf(upk(hprev[g0]), upk(hprev[g0 + 1])),
                               fmaxf(upk(hprev[g0 + 128]), upk(hprev[g0 + 129]))));
            int pi = ((b * 48 + f) * 16 + tp * 2 + y) * 64 + xp;
            unsigned pm = pack_hl(m);
            p2hi[pi] = (unsigned short)pm;
            p2lo[pi] = (unsigned short)(pm >> 16);
        }
    }

    for (int idx = tid; idx < 80 * 54; idx += 256) {
        int ci = idx / 54, rem = idx % 54;
        int dy = rem / 18, lx = rem % 18;
        int gy = y + dy - 1, gx = x0 + lx - 1;
        unsigned u = 0;
        if (gy >= 0 && gy < 4 && gx >= 0 && gx < 128)
            u = (ci < 32) ? p1pk[(((b * 32 + ci) * 16 + t) * 4 + gy) * 128 + gx]
                          : hprev[((b * 48 + (ci - 32)) * 4 + gy) * 128 + gx];
        int k = ci * 3 + dy;
        int a16 = lx * 256 + (((k >> 3) ^ (lx & 15)) << 3) + (k & 7);
        sBhi[a16] = (unsigned short)u;
        sBlo[a16] = (unsigned short)(u >> 16);
    }
    // zero pad slots (k = 240..255)
    for (int e = tid; e < 18 * 16; e += 256) {
        int lx = e >> 4, k = 240 + (e & 15);
        int a16 = lx * 256 + (((k >> 3) ^ (lx & 15)) << 3) + (k & 7);
        sBhi[a16] = 0;
        sBlo[a16] = 0;
    }
    __syncthreads();

    const int l = tid & 63;
    const int wv = __builtin_amdgcn_readfirstlane(tid >> 6);
    const int ln = l & 15, kg = l >> 4;
    f32x4 acc[3] = {{0.f,0.f,0.f,0.f},{0.f,0.f,0.f,0.f},{0.f,0.f,0.f,0.f}};

#pragma unroll
    for (int kk = 0; kk < 8; ++kk) {
        short8 bh[3], bl[3];
#pragma unroll
        for (int dx = 0; dx < 3; ++dx) {
            int lx = ln + dx;
            int boff = lx * 256 + ((((kk << 2) + kg) ^ (lx & 15)) << 3);
            bh[dx] = *(const short8*)&sBhi[boff];
            bl[dx] = *(const short8*)&sBlo[boff];
        }
#pragma unroll
        for (int j = 0; j < 3; ++j) {
            int mt = wv * 3 + j;
#pragma unroll
            for (int dx = 0; dx < 3; ++dx) {
                int aoff = ((((dx * 12 + mt) * 8 + kk) * 4 + kg) * 16 + ln) * 8;
                short8 ah = *(const short8*)&w2F[aoff];
                acc[j] = __builtin_amdgcn_mfma_f32_16x16x32_bf16(ah, bl[dx], acc[j], 0, 0, 0);
                acc[j] = __builtin_amdgcn_mfma_f32_16x16x32_bf16(ah, bh[dx], acc[j], 0, 0, 0);
            }
        }
    }

    const int x = x0 + ln;
#pragma unroll
    for (int j = 0; j < 3; ++j) {
        int mt = wv * 3 + j;
        int f = mt * 4 + kg;
        float zi = acc[j][0] + b2[f];
        float zf = acc[j][1] + b2[48 + f];
        float zg = acc[j][2] + b2[96 + f];
        float zo = acc[j][3] + b2[144 + f];
        int gidx = ((b * 48 + f) * 4 + y) * 128 + x;
        float cv = c2[gidx];
        float cn = sigm(zf) * cv + sigm(zi) * tanh_fast(zg);
        c2[gidx] = cn;
        hout[gidx] = pack_hl(sigm(zo) * tanh_fast(cn));
    }
}

// ---------------- final pool2 for tp=7 ----------------
__global__ void pool2(const unsigned* __restrict__ hA, const unsigned* __restrict__ hB,
                      unsigned short* __restrict__ p2hi, unsigned short* __restrict__ p2lo,
                      int tp)
{
    int idx = blockIdx.x * 256 + threadIdx.x;
    if (idx >= 8 * 48 * 2 * 64) return;
    int xp = idx & 63;
    int t1 = idx >> 6;
    int yp = t1 & 1; t1 >>= 1;
    int f = t1 % 48, b = t1 / 48;
    float m = -INFINITY;
#pragma unroll
    for (int dy = 0; dy < 2; ++dy)
#pragma unroll
        for (int dx = 0; dx < 2; ++dx) {
            int g = ((b * 48 + f) * 4 + yp * 2 + dy) * 128 + xp * 2 + dx;
            m = fmaxf(m, fmaxf(upk(hA[g]), upk(hB[g])));
        }
    int pi = ((b * 48 + f) * 16 + tp * 2 + yp) * 64 + xp;
    unsigned pm = pack_hl(m);
    p2hi[pi] = (unsigned short)pm;
    p2lo[pi] = (unsigned short)(pm >> 16);
}

// ---------------- conv3 (streaming MFMA, 3-term, K-split partials) ----------
__global__ __launch_bounds__(256) void conv3_part(
    const unsigned short* __restrict__ p2hi, const unsigned short* __restrict__ p2lo,
    const unsigned short* __restrict__ w3F,
    float* __restrict__ part)    // (12,256,112)
{
    __shared__ float sRed[4 * 7 * 256];
    const int mq = blockIdx.x, ck = blockIdx.y;
    const int tid = threadIdx.x;
    const int l = tid & 63;
    const int wv = __builtin_amdgcn_readfirstlane(tid >> 6);
    const int c = ck * 4 + wv;
    const int ln = l & 15, kg = l >> 4;

    int rowbase[7];
#pragma unroll
    for (int nt = 0; nt < 7; ++nt) {
        int col = nt * 16 + ln;
        int bi = col / 14, r = col % 14;
        rowbase[nt] = (bi * 48 + c) * 16 + r;
    }

    f32x4 acc[7];
#pragma unroll
    for (int nt = 0; nt < 7; ++nt) acc[nt] = (f32x4){0.f, 0.f, 0.f, 0.f};

#pragma unroll
    for (int kk = 0; kk < 6; ++kk) {
        int aoff = ((((mq * 48 + c) * 6 + kk) * 4 + kg) * 16 + ln) * 8;
        short8 ah = *(const short8*)&w3F[aoff];
        short8 al = *(const short8*)&w3F[PLANE_W3 + aoff];
        int s = kk * 4 + kg;
        int dr = s >> 3, w0 = (s & 7) * 8;
#pragma unroll
        for (int nt = 0; nt < 7; ++nt) {
            int boff = (rowbase[nt] + dr) * 64 + w0;
            short8 bh = *(const short8*)&p2hi[boff];
            short8 bl = *(const short8*)&p2lo[boff];
            acc[nt] = __builtin_amdgcn_mfma_f32_16x16x32_bf16(al, bh, acc[nt], 0, 0, 0);
            acc[nt] = __builtin_amdgcn_mfma_f32_16x16x32_bf16(ah, bl, acc[nt], 0, 0, 0);
            acc[nt] = __builtin_amdgcn_mfma_f32_16x16x32_bf16(ah, bh, acc[nt], 0, 0, 0);
        }
    }

#pragma unroll
    for (int nt = 0; nt < 7; ++nt)
        *(f32x4*)&sRed[wv * 1792 + nt * 256 + l * 4] = acc[nt];
    __syncthreads();

#pragma unroll
    for (int nt = 0; nt < 7; ++nt) {
        float s = sRed[nt * 256 + tid] + sRed[1792 + nt * 256 + tid] +
                  sRed[2 * 1792 + nt * 256 + tid] + sRed[3 * 1792 + nt * 256 + tid];
        int r16 = (tid >> 6) * 4 + (tid & 3);
        int m = mq * 16 + r16;
        int col = nt * 16 + ((tid >> 2) & 15);
        part[(ck * 256 + m) * 112 + col] = s;
    }
}

// ---------------- head: reduce+bias+ELU -> conv4+ELU -> conv5 ----------------
__global__ __launch_bounds__(256) void head(
    const float* __restrict__ part, const float* __restrict__ b3,
    const float* __restrict__ w4T, const float* __restrict__ b4,
    const float* __restrict__ w5T, const float* __restrict__ b5,
    float* __restrict__ out)
{
    __shared__ float sO3[256];
    __shared__ float sO4[128];
    const int col = blockIdx.x;          // b*14 + r
    const int b = col / 14, r = col % 14;
    const int tid = threadIdx.x;

    float s = b3[tid];
#pragma unroll
    for (int ck = 0; ck < 12; ++ck)
        s += part[(ck * 256 + tid) * 112 + col];
    sO3[tid] = elu(s);
    __syncthreads();

    if (tid < 128) {
        float a4 = b4[tid];
        for (int c = 0; c < 256; ++c)
            a4 = fmaf(sO3[c], w4T[c * 128 + tid], a4);
        sO4[tid] = elu(a4);
    }
    __syncthreads();

    if (tid < 88) {
        float a5 = b5[tid];
        for (int c = 0; c < 128; ++c)
            a5 = fmaf(sO4[c], w5T[c * 88 + tid], a5);
        out[(b * 88 + tid) * 14 + r] = a5;
    }
}

// ---------------- prep: x pack + weight prepacks ----------------
__global__ void prep(const float* __restrict__ x, const float* __restrict__ w1,
                     const float* __restrict__ w2, const float* __restrict__ w3,
                     const float* __restrict__ w4, const float* __restrict__ w5,
                     unsigned* __restrict__ xpk,
                     unsigned short* __restrict__ w1F, unsigned short* __restrict__ w2F,
                     unsigned short* __restrict__ w3F,
                     float* __restrict__ w4T, float* __restrict__ w5T)
{
    int i = blockIdx.x * 256 + threadIdx.x;
    if (i < 131072) {          // x -> packed u32, 4 per thread
        const float4 v = *(const float4*)&x[i * 4];
        uint4 o;
        o.x = pack_hl(v.x); o.y = pack_hl(v.y);
        o.z = pack_hl(v.z); o.w = pack_hl(v.w);
        *(uint4*)&xpk[i * 4] = o;
        return;
    }
    i -= 131072;
    if (i < 6144) {            // w1F hi: [dx][mt 8][kk 4][kg 4][ln 16][8]
        int base = i * 8;
        int dx = base / 16384, rem = base % 16384;
        int mt = rem / 2048, r2 = rem % 2048;
        int kk = r2 / 512, r3 = r2 % 512;
        int kg = r3 / 128, ln = (r3 % 128) / 8;
        int f = mt * 4 + (ln >> 2), gate = ln & 3;
        int co = gate * 32 + f;
        int k0 = kk * 32 + kg * 8;
        short8 h;
#pragma unroll
        for (int e = 0; e < 8; ++e) {
            int k = k0 + e;
            float v = (k < 99) ? w1[co * 297 + (k / 3) * 9 + (k % 3) * 3 + dx] : 0.0f;
            h[e] = (short)bf16_rne(v);
        }
        *(short8*)&w1F[base] = h;
        return;
    }
    i -= 6144;
    if (i < 18432) {           // w2F hi: [dx][mt 12][kk 8][kg 4][ln 16][8]
        int base = i * 8;
        int dx = base / 49152, rem = base % 49152;
        int mt = rem / 4096, r2 = rem % 4096;
        int kk = r2 / 512, r3 = r2 % 512;
        int kg = r3 / 128, ln = (r3 % 128) / 8;
        int f = mt * 4 + (ln >> 2), gate = ln & 3;
        int co = gate * 48 + f;
        int k0 = kk * 32 + kg * 8;
        short8 h;
#pragma unroll
        for (int e = 0; e < 8; ++e) {
            int k = k0 + e;
            float v = (k < 240) ? w2[co * 720 + (k / 3) * 9 + (k % 3) * 3 + dx] : 0.0f;
            h[e] = (short)bf16_rne(v);
        }
        *(short8*)&w2F[base] = h;
        return;
    }
    i -= 18432;
    if (i < 294912) {          // w3F hi+lo: [mq 16][c 48][kk 6][kg 4][ln 16][8]
        int base = i * 8;
        int mq = base / 147456, rem = base % 147456;
        int c = rem / 3072, r2 = rem % 3072;
        int kk = r2 / 512, r3 = r2 % 512;
        int kg = r3 / 128, ln = (r3 % 128) / 8;
        int m = mq * 16 + ln;
        int kc0 = kk * 32 + kg * 8;
        int dr = kc0 >> 6, w0 = kc0 & 63;
        const float* src = &w3[((m * 48 + c) * 3 + dr) * 64 + w0];
        short8 hh, hl;
#pragma unroll
        for (int e = 0; e < 8; ++e) {
            float v = src[e];
            unsigned short hi = bf16_rne(v);
            hh[e] = (short)hi;
            hl[e] = (short)bf16_rne(v - bf16_to_f(hi));
        }
        *(short8*)&w3F[base] = hh;
        *(short8*)&w3F[PLANE_W3 + base] = hl;
        return;
    }
    i -= 294912;
    if (i < 32768) {           // w4 (128,256) -> w4T (256,128)
        int n = i / 256, cch = i % 256;
        w4T[cch * 128 + n] = w4[i];
        return;
    }
    i -= 32768;
    if (i < 11264) {           // w5 (88,128) -> w5T (128,88)
        int n = i / 128, cch = i % 128;
        w5T[cch * 88 + n] = w5[i];
    }
}

extern "C" void kernel_launch(void* const* d_in, const int* in_sizes, int n_in,
                              void* d_out, int out_size, void* d_ws, size_t ws_size,
                              hipStream_t stream)
{
    const float* x  = (const float*)d_in[0];
    const float* w1 = (const float*)d_in[1];
    const float* b1 = (const float*)d_in[2];
    const float* w2 = (const float*)d_in[3];
    const float* b2 = (const float*)d_in[4];
    const float* w3 = (const float*)d_in[5];
    const float* b3 = (const float*)d_in[6];
    const float* w4 = (const float*)d_in[7];
    const float* b4 = (const float*)d_in[8];
    const float* w5 = (const float*)d_in[9];
    const float* b5 = (const float*)d_in[10];
    float* out = (float*)d_out;

    float* ws = (float*)d_ws;
    size_t off = 0;
    auto alloc = [&](size_t n) { float* p = ws + off; off += n; return p; };
    unsigned* h1[3];
    h1[0] = (unsigned*)alloc(524288); h1[1] = (unsigned*)alloc(524288);
    h1[2] = (unsigned*)alloc(524288);
    float* c1 = alloc(524288);
    unsigned* xpk = (unsigned*)alloc(524288);               // (8,32,8,256) packed
    unsigned* p1pk = (unsigned*)alloc(2097152);             // (8,32,16,4,128) u32
    unsigned* h2[3];
    h2[0] = (unsigned*)alloc(196608); h2[1] = (unsigned*)alloc(196608);
    h2[2] = (unsigned*)alloc(196608);
    float* c2 = alloc(196608);
    unsigned short* p2hi = (unsigned short*)alloc(196608);  // 393216 u16
    unsigned short* p2lo = (unsigned short*)alloc(196608);
    float* part = alloc(344064);                            // (12,256,112)
    unsigned short* w1F = (unsigned short*)alloc(24576);    // 49152 u16 (hi)
    unsigned short* w2F = (unsigned short*)alloc(73728);    // 147456 u16 (hi)
    unsigned short* w3F = (unsigned short*)alloc(2359296);  // hi+lo planes
    float* w4T = alloc(32768);
    float* w5T = alloc(11264);
    (void)ws_size; (void)off;  // ~35 MB total

    hipMemsetAsync(h1[2], 0, 524288 * sizeof(unsigned), stream);
    hipMemsetAsync(c1,    0, 524288 * sizeof(float), stream);
    hipMemsetAsync(h2[2], 0, 196608 * sizeof(unsigned), stream);
    hipMemsetAsync(c2,    0, 196608 * sizeof(float), stream);

    prep<<<1932, 256, 0, stream>>>(x, w1, w2, w3, w4, w5, xpk,
                                   w1F, w2F, w3F, w4T, w5T);

    for (int t = 0; t < 32; ++t) {
        lstm1_step<<<dim3(8, 8, 8), 256, 0, stream>>>(
            xpk, w1F, b1, h1[(t + 2) % 3], h1[(t + 1) % 3], h1[t % 3], c1,
            p1pk, t);
    }
    pool1k<<<512, 256, 0, stream>>>(h1[0], h1[1], p1pk, 15); // t=30,31

    for (int t = 0; t < 16; ++t) {
        lstm2_step<<<dim3(8, 4, 8), 256, 0, stream>>>(
            p1pk, w2F, b2, h2[(t + 2) % 3], h2[(t + 1) % 3], c2, h2[t % 3],
            p2hi, p2lo, t);
    }
    pool2<<<192, 256, 0, stream>>>(h2[2], h2[0], p2hi, p2lo, 7);   // t=14,15

    conv3_part<<<dim3(16, 12), 256, 0, stream>>>(p2hi, p2lo, w3F, part);
    head<<<112, 256, 0, stream>>>(part, b3, w4T, b4, w5T, b5, out);
}

// Round 11
// 484.198 us; speedup vs baseline: 3.2159x; 1.3104x over previous
//
#include <hip/hip_runtime.h>
#include <math.h>

// Net: ConvLSTM(32)->pool->ConvLSTM(48)->pool->conv3+ELU->conv4(1x1)+ELU->conv5(1x1)
// B=8, T=32, H=8, W=256, F1=32, F2=48, F3=256, F4=128, NNOTE=88
// R11: lstm2 steps EMBEDDED into lstm1 launches (deps all cross >=1 kernel
//      boundary: lstm2(tp) in kernel t=2tp+4 reads p1[tp] written at t=2tp+2
//      and h2 written at t-2). 53 -> 38 launches. Memsets folded into prep.
//      Numerics identical to R9/R10.

#define DEVINL static __device__ __forceinline__
typedef __attribute__((ext_vector_type(8))) short short8;
typedef __attribute__((ext_vector_type(4))) float f32x4;

#define PLANE_W3 2359296    // w3F (16*48*6*4*16*8), hi plane size (lo follows)

DEVINL float sigm(float x) { return 1.0f / (1.0f + __expf(-x)); }
DEVINL float tanh_fast(float x) { return 1.0f - 2.0f / (__expf(2.0f * x) + 1.0f); }
DEVINL float elu(float x) { return x > 0.0f ? x : expm1f(x); }
DEVINL unsigned short bf16_rne(float v) {
    unsigned u = __float_as_uint(v);
    unsigned r = (u + 0x7FFF + ((u >> 16) & 1)) >> 16;
    return (unsigned short)r;
}
DEVINL float bf16_to_f(unsigned short h) { return __uint_as_float(((unsigned)h) << 16); }
DEVINL unsigned pack_hl(float v) {
    unsigned short hi = bf16_rne(v);
    unsigned short lo = bf16_rne(v - bf16_to_f(hi));
    return (unsigned)hi | ((unsigned)lo << 16);
}
DEVINL float upk(unsigned u) {
    return __uint_as_float(u << 16) + __uint_as_float(u & 0xffff0000u);
}

// ---------------- LSTM1 step body (MFMA, 2-term split) ----------------
// (xq,y,b) tile: 32-wide x-tile; block 256 = 4 waves; wave wv: 2 mt x 2 nt.
DEVINL void lstm1_body(
    int xq, int y, int b, int t,
    const unsigned* __restrict__ xpk, const unsigned short* __restrict__ w1F,
    const float* __restrict__ b1,
    const unsigned* __restrict__ hprev, const unsigned* __restrict__ hpool,
    unsigned* __restrict__ hout, float* __restrict__ c1,
    unsigned* __restrict__ p1pk)
{
    __shared__ __align__(16) unsigned short sBhi[34 * 128];
    __shared__ __align__(16) unsigned short sBlo[34 * 128];
    const int x0 = xq * 32;
    const int tid = threadIdx.x;

    // fused pool of pair (t-2, t-1) -> p1[tp], odd-y blocks (16 xp each)
    if (((t & 1) == 0) && t >= 2 && (y & 1) == 1) {
        int tp = (t >> 1) - 1, yp = y >> 1;
        for (int e = tid; e < 512; e += 256) {
            int f = e >> 4, xl = e & 15;
            int xp = (x0 >> 1) + xl, gx = x0 + 2 * xl;
            int b0 = ((b * 32 + f) * 8 + (y - 1)) * 256 + gx;
            float m = upk(hpool[b0]);
            m = fmaxf(m, upk(hpool[b0 + 1]));
            m = fmaxf(m, upk(hpool[b0 + 256]));
            m = fmaxf(m, upk(hpool[b0 + 257]));
            m = fmaxf(m, upk(hprev[b0]));
            m = fmaxf(m, upk(hprev[b0 + 1]));
            m = fmaxf(m, upk(hprev[b0 + 256]));
            m = fmaxf(m, upk(hprev[b0 + 257]));
            p1pk[(((b * 32 + f) * 16 + tp) * 4 + yp) * 128 + xp] = pack_hl(m);
        }
    }

    // stage input tile: packed u32 -> hi/lo planes (swizzled)
    for (int e = tid; e < 34 * 128; e += 256) {
        int lx = e % 34, kk = e / 34;
        unsigned u = 0;
        if (kk < 99) {
            int ci = kk / 3, dy = kk - ci * 3;
            int gy = y + dy - 1, gx = x0 + lx - 1;
            if (gy >= 0 && gy < 8 && gx >= 0 && gx < 256)
                u = (ci == 0) ? xpk[((b * 32 + t) * 8 + gy) * 256 + gx]
                              : hprev[((b * 32 + (ci - 1)) * 8 + gy) * 256 + gx];
        }
        int a16 = lx * 128 + (((kk >> 3) ^ (lx & 15)) << 3) + (kk & 7);
        sBhi[a16] = (unsigned short)u;
        sBlo[a16] = (unsigned short)(u >> 16);
    }
    __syncthreads();

    const int l = tid & 63;
    const int wv = __builtin_amdgcn_readfirstlane(tid >> 6); // 0..3
    const int ln = l & 15, kg = l >> 4;
    f32x4 acc[2][2];
#pragma unroll
    for (int i = 0; i < 2; ++i)
#pragma unroll
        for (int j = 0; j < 2; ++j) acc[i][j] = (f32x4){0.f, 0.f, 0.f, 0.f};

#pragma unroll
    for (int kk = 0; kk < 4; ++kk) {
        short8 bh[2][3], bl[2][3];
#pragma unroll
        for (int ntl = 0; ntl < 2; ++ntl)
#pragma unroll
            for (int dx = 0; dx < 3; ++dx) {
                int lx = ntl * 16 + ln + dx;
                int slot = kk * 4 + kg;
                int boff = lx * 128 + ((slot ^ (lx & 15)) << 3);
                bh[ntl][dx] = *(const short8*)&sBhi[boff];
                bl[ntl][dx] = *(const short8*)&sBlo[boff];
            }
#pragma unroll
        for (int mtl = 0; mtl < 2; ++mtl)
#pragma unroll
            for (int dx = 0; dx < 3; ++dx) {
                int aoff = ((((dx * 8 + wv * 2 + mtl) * 4 + kk) * 4 + kg) * 16 + ln) * 8;
                short8 ah = *(const short8*)&w1F[aoff];
#pragma unroll
                for (int ntl = 0; ntl < 2; ++ntl) {
                    acc[mtl][ntl] = __builtin_amdgcn_mfma_f32_16x16x32_bf16(ah, bl[ntl][dx], acc[mtl][ntl], 0, 0, 0);
                    acc[mtl][ntl] = __builtin_amdgcn_mfma_f32_16x16x32_bf16(ah, bh[ntl][dx], acc[mtl][ntl], 0, 0, 0);
                }
            }
    }

#pragma unroll
    for (int mtl = 0; mtl < 2; ++mtl) {
        const int f = (wv * 2 + mtl) * 4 + kg;
        const float bi = b1[f], bff = b1[32 + f], bg = b1[64 + f], bo = b1[96 + f];
#pragma unroll
        for (int ntl = 0; ntl < 2; ++ntl) {
            f32x4 a = acc[mtl][ntl];
            int gidx = ((b * 32 + f) * 8 + y) * 256 + x0 + ntl * 16 + ln;
            float zi = a[0] + bi, zf = a[1] + bff, zg = a[2] + bg, zo = a[3] + bo;
            float cv = c1[gidx];
            float cn = sigm(zf) * cv + sigm(zi) * tanh_fast(zg);
            c1[gidx] = cn;
            hout[gidx] = pack_hl(sigm(zo) * tanh_fast(cn));
        }
    }
}

// ---------------- LSTM2 step body (MFMA, 2-term, gates + pool fused) --------
DEVINL void lstm2_body(
    int xq, int y, int b, int t,
    const unsigned* __restrict__ p1pk, const unsigned short* __restrict__ w2F,
    const float* __restrict__ b2,
    const unsigned* __restrict__ hprev, const unsigned* __restrict__ hpool,
    float* __restrict__ c2, unsigned* __restrict__ hout,
    unsigned short* __restrict__ p2hi, unsigned short* __restrict__ p2lo)
{
    __shared__ __align__(16) unsigned short sChi[18 * 256];
    __shared__ __align__(16) unsigned short sClo[18 * 256];
    const int x0 = xq * 16;
    const int tid = threadIdx.x;

    if (((t & 1) == 0) && t >= 2 && y < 2) {
        int tp = (t >> 1) - 1;
        for (int e = tid; e < 48 * 8; e += 256) {
            int f = e >> 3, xl = e & 7;
            int xp = xq * 8 + xl;
            int g0 = ((b * 48 + f) * 4 + y * 2) * 128 + xp * 2;
            float m = fmaxf(fmaxf(upk(hpool[g0]), upk(hpool[g0 + 1])),
                            fmaxf(upk(hpool[g0 + 128]), upk(hpool[g0 + 129])));
            m = fmaxf(m, fmaxf(fmaxf(upk(hprev[g0]), upk(hprev[g0 + 1])),
                               fmaxf(upk(hprev[g0 + 128]), upk(hprev[g0 + 129]))));
            int pi = ((b * 48 + f) * 16 + tp * 2 + y) * 64 + xp;
            unsigned pm = pack_hl(m);
            p2hi[pi] = (unsigned short)pm;
            p2lo[pi] = (unsigned short)(pm >> 16);
        }
    }

    for (int idx = tid; idx < 80 * 54; idx += 256) {
        int ci = idx / 54, rem = idx % 54;
        int dy = rem / 18, lx = rem % 18;
        int gy = y + dy - 1, gx = x0 + lx - 1;
        unsigned u = 0;
        if (gy >= 0 && gy < 4 && gx >= 0 && gx < 128)
            u = (ci < 32) ? p1pk[(((b * 32 + ci) * 16 + t) * 4 + gy) * 128 + gx]
                          : hprev[((b * 48 + (ci - 32)) * 4 + gy) * 128 + gx];
        int k = ci * 3 + dy;
        int a16 = lx * 256 + (((k >> 3) ^ (lx & 15)) << 3) + (k & 7);
        sChi[a16] = (unsigned short)u;
        sClo[a16] = (unsigned short)(u >> 16);
    }
    for (int e = tid; e < 18 * 16; e += 256) {
        int lx = e >> 4, k = 240 + (e & 15);
        int a16 = lx * 256 + (((k >> 3) ^ (lx & 15)) << 3) + (k & 7);
        sChi[a16] = 0;
        sClo[a16] = 0;
    }
    __syncthreads();

    const int l = tid & 63;
    const int wv = __builtin_amdgcn_readfirstlane(tid >> 6);
    const int ln = l & 15, kg = l >> 4;
    f32x4 acc[3] = {{0.f,0.f,0.f,0.f},{0.f,0.f,0.f,0.f},{0.f,0.f,0.f,0.f}};

#pragma unroll
    for (int kk = 0; kk < 8; ++kk) {
        short8 bh[3], bl[3];
#pragma unroll
        for (int dx = 0; dx < 3; ++dx) {
            int lx = ln + dx;
            int boff = lx * 256 + ((((kk << 2) + kg) ^ (lx & 15)) << 3);
            bh[dx] = *(const short8*)&sChi[boff];
            bl[dx] = *(const short8*)&sClo[boff];
        }
#pragma unroll
        for (int j = 0; j < 3; ++j) {
            int mt = wv * 3 + j;
#pragma unroll
            for (int dx = 0; dx < 3; ++dx) {
                int aoff = ((((dx * 12 + mt) * 8 + kk) * 4 + kg) * 16 + ln) * 8;
                short8 ah = *(const short8*)&w2F[aoff];
                acc[j] = __builtin_amdgcn_mfma_f32_16x16x32_bf16(ah, bl[dx], acc[j], 0, 0, 0);
                acc[j] = __builtin_amdgcn_mfma_f32_16x16x32_bf16(ah, bh[dx], acc[j], 0, 0, 0);
            }
        }
    }

    const int x = x0 + ln;
#pragma unroll
    for (int j = 0; j < 3; ++j) {
        int mt = wv * 3 + j;
        int f = mt * 4 + kg;
        float zi = acc[j][0] + b2[f];
        float zf = acc[j][1] + b2[48 + f];
        float zg = acc[j][2] + b2[96 + f];
        float zo = acc[j][3] + b2[144 + f];
        int gidx = ((b * 48 + f) * 4 + y) * 128 + x;
        float cv = c2[gidx];
        float cn = sigm(zf) * cv + sigm(zi) * tanh_fast(zg);
        c2[gidx] = cn;
        hout[gidx] = pack_hl(sigm(zo) * tanh_fast(cn));
    }
}

// ---------------- combined step kernel ----------------
// grid 768 (lstm2 active): blocks [0,256) = lstm2(t2), [256,768) = lstm1(t).
// grid 512: all lstm1. lstm2-role blocks are dispatched FIRST so they overlap.
__global__ __launch_bounds__(256) void step_k(
    const unsigned* __restrict__ xpk, const unsigned short* __restrict__ w1F,
    const float* __restrict__ b1,
    const unsigned* __restrict__ hprev1, const unsigned* __restrict__ hpool1,
    unsigned* __restrict__ hout1, float* __restrict__ c1,
    unsigned* __restrict__ p1pk,
    const unsigned short* __restrict__ w2F, const float* __restrict__ b2,
    const unsigned* __restrict__ hprev2, const unsigned* __restrict__ hpool2,
    unsigned* __restrict__ hout2, float* __restrict__ c2,
    unsigned short* __restrict__ p2hi, unsigned short* __restrict__ p2lo,
    int t, int t2)
{
    int bid = blockIdx.x;
    if (gridDim.x == 768) {
        if (bid < 256) {
            lstm2_body(bid & 7, (bid >> 3) & 3, bid >> 5, t2,
                       p1pk, w2F, b2, hprev2, hpool2, c2, hout2, p2hi, p2lo);
            return;
        }
        bid -= 256;
    }
    lstm1_body(bid & 7, (bid >> 3) & 7, bid >> 6, t,
               xpk, w1F, b1, hprev1, hpool1, hout1, c1, p1pk);
}

// ---------------- standalone lstm2 (tp=15) ----------------
__global__ __launch_bounds__(256) void lstm2_k(
    const unsigned* __restrict__ p1pk, const unsigned short* __restrict__ w2F,
    const float* __restrict__ b2,
    const unsigned* __restrict__ hprev, const unsigned* __restrict__ hpool,
    float* __restrict__ c2, unsigned* __restrict__ hout,
    unsigned short* __restrict__ p2hi, unsigned short* __restrict__ p2lo, int t)
{
    int bid = blockIdx.x;
    lstm2_body(bid & 7, (bid >> 3) & 3, bid >> 5, t,
               p1pk, w2F, b2, hprev, hpool, c2, hout, p2hi, p2lo);
}

// ---------------- final pool1 for tp=15 ----------------
__global__ void pool1k(const unsigned* __restrict__ hA, const unsigned* __restrict__ hB,
                       unsigned* __restrict__ p1pk, int tp)
{
    int idx = blockIdx.x * 256 + threadIdx.x;
    if (idx >= 8 * 32 * 4 * 128) return;
    int xp = idx & 127, t1 = idx >> 7;
    int yp = t1 & 3, t2 = t1 >> 2;
    int f = t2 & 31, b = t2 >> 5;
    int base = ((b * 32 + f) * 8 + yp * 2) * 256 + xp * 2;
    float m = upk(hA[base]);
    m = fmaxf(m, upk(hA[base + 1]));
    m = fmaxf(m, upk(hA[base + 256]));
    m = fmaxf(m, upk(hA[base + 257]));
    m = fmaxf(m, upk(hB[base]));
    m = fmaxf(m, upk(hB[base + 1]));
    m = fmaxf(m, upk(hB[base + 256]));
    m = fmaxf(m, upk(hB[base + 257]));
    p1pk[(((b * 32 + f) * 16 + tp) * 4 + yp) * 128 + xp] = pack_hl(m);
}

// ---------------- final pool2 for tp=7 ----------------
__global__ void pool2(const unsigned* __restrict__ hA, const unsigned* __restrict__ hB,
                      unsigned short* __restrict__ p2hi, unsigned short* __restrict__ p2lo,
                      int tp)
{
    int idx = blockIdx.x * 256 + threadIdx.x;
    if (idx >= 8 * 48 * 2 * 64) return;
    int xp = idx & 63;
    int t1 = idx >> 6;
    int yp = t1 & 1; t1 >>= 1;
    int f = t1 % 48, b = t1 / 48;
    float m = -INFINITY;
#pragma unroll
    for (int dy = 0; dy < 2; ++dy)
#pragma unroll
        for (int dx = 0; dx < 2; ++dx) {
            int g = ((b * 48 + f) * 4 + yp * 2 + dy) * 128 + xp * 2 + dx;
            m = fmaxf(m, fmaxf(upk(hA[g]), upk(hB[g])));
        }
    int pi = ((b * 48 + f) * 16 + tp * 2 + yp) * 64 + xp;
    unsigned pm = pack_hl(m);
    p2hi[pi] = (unsigned short)pm;
    p2lo[pi] = (unsigned short)(pm >> 16);
}

// ---------------- conv3 (streaming MFMA, 3-term, K-split partials) ----------
__global__ __launch_bounds__(256) void conv3_part(
    const unsigned short* __restrict__ p2hi, const unsigned short* __restrict__ p2lo,
    const unsigned short* __restrict__ w3F,
    float* __restrict__ part)    // (12,256,112)
{
    __shared__ float sRed[4 * 7 * 256];
    const int mq = blockIdx.x, ck = blockIdx.y;
    const int tid = threadIdx.x;
    const int l = tid & 63;
    const int wv = __builtin_amdgcn_readfirstlane(tid >> 6);
    const int c = ck * 4 + wv;
    const int ln = l & 15, kg = l >> 4;

    int rowbase[7];
#pragma unroll
    for (int nt = 0; nt < 7; ++nt) {
        int col = nt * 16 + ln;
        int bi = col / 14, r = col % 14;
        rowbase[nt] = (bi * 48 + c) * 16 + r;
    }

    f32x4 acc[7];
#pragma unroll
    for (int nt = 0; nt < 7; ++nt) acc[nt] = (f32x4){0.f, 0.f, 0.f, 0.f};

#pragma unroll
    for (int kk = 0; kk < 6; ++kk) {
        int aoff = ((((mq * 48 + c) * 6 + kk) * 4 + kg) * 16 + ln) * 8;
        short8 ah = *(const short8*)&w3F[aoff];
        short8 al = *(const short8*)&w3F[PLANE_W3 + aoff];
        int s = kk * 4 + kg;
        int dr = s >> 3, w0 = (s & 7) * 8;
#pragma unroll
        for (int nt = 0; nt < 7; ++nt) {
            int boff = (rowbase[nt] + dr) * 64 + w0;
            short8 bh = *(const short8*)&p2hi[boff];
            short8 bl = *(const short8*)&p2lo[boff];
            acc[nt] = __builtin_amdgcn_mfma_f32_16x16x32_bf16(al, bh, acc[nt], 0, 0, 0);
            acc[nt] = __builtin_amdgcn_mfma_f32_16x16x32_bf16(ah, bl, acc[nt], 0, 0, 0);
            acc[nt] = __builtin_amdgcn_mfma_f32_16x16x32_bf16(ah, bh, acc[nt], 0, 0, 0);
        }
    }

#pragma unroll
    for (int nt = 0; nt < 7; ++nt)
        *(f32x4*)&sRed[wv * 1792 + nt * 256 + l * 4] = acc[nt];
    __syncthreads();

#pragma unroll
    for (int nt = 0; nt < 7; ++nt) {
        float s = sRed[nt * 256 + tid] + sRed[1792 + nt * 256 + tid] +
                  sRed[2 * 1792 + nt * 256 + tid] + sRed[3 * 1792 + nt * 256 + tid];
        int r16 = (tid >> 6) * 4 + (tid & 3);
        int m = mq * 16 + r16;
        int col = nt * 16 + ((tid >> 2) & 15);
        part[(ck * 256 + m) * 112 + col] = s;
    }
}

// ---------------- head: reduce+bias+ELU -> conv4+ELU -> conv5 ----------------
__global__ __launch_bounds__(256) void head(
    const float* __restrict__ part, const float* __restrict__ b3,
    const float* __restrict__ w4T, const float* __restrict__ b4,
    const float* __restrict__ w5T, const float* __restrict__ b5,
    float* __restrict__ out)
{
    __shared__ float sO3[256];
    __shared__ float sO4[128];
    const int col = blockIdx.x;          // b*14 + r
    const int b = col / 14, r = col % 14;
    const int tid = threadIdx.x;

    float s = b3[tid];
#pragma unroll
    for (int ck = 0; ck < 12; ++ck)
        s += part[(ck * 256 + tid) * 112 + col];
    sO3[tid] = elu(s);
    __syncthreads();

    if (tid < 128) {
        float a4 = b4[tid];
        for (int c = 0; c < 256; ++c)
            a4 = fmaf(sO3[c], w4T[c * 128 + tid], a4);
        sO4[tid] = elu(a4);
    }
    __syncthreads();

    if (tid < 88) {
        float a5 = b5[tid];
        for (int c = 0; c < 128; ++c)
            a5 = fmaf(sO4[c], w5T[c * 88 + tid], a5);
        out[(b * 88 + tid) * 14 + r] = a5;
    }
}

// ---------------- prep: zero-init + x pack + weight prepacks ----------------
__global__ void prep(const float* __restrict__ x, const float* __restrict__ w1,
                     const float* __restrict__ w2, const float* __restrict__ w3,
                     const float* __restrict__ w4, const float* __restrict__ w5,
                     unsigned* __restrict__ zeroA,  // h1[2]+c1, 1048576 u32
                     unsigned* __restrict__ zeroB,  // h2[2]+c2, 393216 u32
                     unsigned* __restrict__ xpk,
                     unsigned short* __restrict__ w1F, unsigned short* __restrict__ w2F,
                     unsigned short* __restrict__ w3F,
                     float* __restrict__ w4T, float* __restrict__ w5T)
{
    int i = blockIdx.x * 256 + threadIdx.x;
    if (i < 65536) {           // zero h1[2] + c1 (16 u32 per thread)
        uint4 z = {0, 0, 0, 0};
        uint4* p = (uint4*)&zeroA[i * 16];
        p[0] = z; p[1] = z; p[2] = z; p[3] = z;
        return;
    }
    i -= 65536;
    if (i < 24576) {           // zero h2[2] + c2
        uint4 z = {0, 0, 0, 0};
        uint4* p = (uint4*)&zeroB[i * 16];
        p[0] = z; p[1] = z; p[2] = z; p[3] = z;
        return;
    }
    i -= 24576;
    if (i < 131072) {          // x -> packed u32, 4 per thread
        const float4 v = *(const float4*)&x[i * 4];
        uint4 o;
        o.x = pack_hl(v.x); o.y = pack_hl(v.y);
        o.z = pack_hl(v.z); o.w = pack_hl(v.w);
        *(uint4*)&xpk[i * 4] = o;
        return;
    }
    i -= 131072;
    if (i < 6144) {            // w1F hi: [dx][mt 8][kk 4][kg 4][ln 16][8]
        int base = i * 8;
        int dx = base / 16384, rem = base % 16384;
        int mt = rem / 2048, r2 = rem % 2048;
        int kk = r2 / 512, r3 = r2 % 512;
        int kg = r3 / 128, ln = (r3 % 128) / 8;
        int f = mt * 4 + (ln >> 2), gate = ln & 3;
        int co = gate * 32 + f;
        int k0 = kk * 32 + kg * 8;
        short8 h;
#pragma unroll
        for (int e = 0; e < 8; ++e) {
            int k = k0 + e;
            float v = (k < 99) ? w1[co * 297 + (k / 3) * 9 + (k % 3) * 3 + dx] : 0.0f;
            h[e] = (short)bf16_rne(v);
        }
        *(short8*)&w1F[base] = h;
        return;
    }
    i -= 6144;
    if (i < 18432) {           // w2F hi: [dx][mt 12][kk 8][kg 4][ln 16][8]
        int base = i * 8;
        int dx = base / 49152, rem = base % 49152;
        int mt = rem / 4096, r2 = rem % 4096;
        int kk = r2 / 512, r3 = r2 % 512;
        int kg = r3 / 128, ln = (r3 % 128) / 8;
        int f = mt * 4 + (ln >> 2), gate = ln & 3;
        int co = gate * 48 + f;
        int k0 = kk * 32 + kg * 8;
        short8 h;
#pragma unroll
        for (int e = 0; e < 8; ++e) {
            int k = k0 + e;
            float v = (k < 240) ? w2[co * 720 + (k / 3) * 9 + (k % 3) * 3 + dx] : 0.0f;
            h[e] = (short)bf16_rne(v);
        }
        *(short8*)&w2F[base] = h;
        return;
    }
    i -= 18432;
    if (i < 294912) {          // w3F hi+lo: [mq 16][c 48][kk 6][kg 4][ln 16][8]
        int base = i * 8;
        int mq = base / 147456, rem = base % 147456;
        int c = rem / 3072, r2 = rem % 3072;
        int kk = r2 / 512, r3 = r2 % 512;
        int kg = r3 / 128, ln = (r3 % 128) / 8;
        int m = mq * 16 + ln;
        int kc0 = kk * 32 + kg * 8;
        int dr = kc0 >> 6, w0 = kc0 & 63;
        const float* src = &w3[((m * 48 + c) * 3 + dr) * 64 + w0];
        short8 hh, hl;
#pragma unroll
        for (int e = 0; e < 8; ++e) {
            float v = src[e];
            unsigned short hi = bf16_rne(v);
            hh[e] = (short)hi;
            hl[e] = (short)bf16_rne(v - bf16_to_f(hi));
        }
        *(short8*)&w3F[base] = hh;
        *(short8*)&w3F[PLANE_W3 + base] = hl;
        return;
    }
    i -= 294912;
    if (i < 32768) {           // w4 (128,256) -> w4T (256,128)
        int n = i / 256, cch = i % 256;
        w4T[cch * 128 + n] = w4[i];
        return;
    }
    i -= 32768;
    if (i < 11264) {           // w5 (88,128) -> w5T (128,88)
        int n = i / 128, cch = i % 128;
        w5T[cch * 88 + n] = w5[i];
    }
}

extern "C" void kernel_launch(void* const* d_in, const int* in_sizes, int n_in,
                              void* d_out, int out_size, void* d_ws, size_t ws_size,
                              hipStream_t stream)
{
    const float* x  = (const float*)d_in[0];
    const float* w1 = (const float*)d_in[1];
    const float* b1 = (const float*)d_in[2];
    const float* w2 = (const float*)d_in[3];
    const float* b2 = (const float*)d_in[4];
    const float* w3 = (const float*)d_in[5];
    const float* b3 = (const float*)d_in[6];
    const float* w4 = (const float*)d_in[7];
    const float* b4 = (const float*)d_in[8];
    const float* w5 = (const float*)d_in[9];
    const float* b5 = (const float*)d_in[10];
    float* out = (float*)d_out;

    float* ws = (float*)d_ws;
    size_t off = 0;
    auto alloc = [&](size_t n) { float* p = ws + off; off += n; return p; };
    unsigned* h1[3];
    h1[0] = (unsigned*)alloc(524288); h1[1] = (unsigned*)alloc(524288);
    h1[2] = (unsigned*)alloc(524288);
    float* c1 = alloc(524288);        // contiguous after h1[2] -> zeroA
    unsigned* xpk = (unsigned*)alloc(524288);
    unsigned* p1pk = (unsigned*)alloc(2097152);
    unsigned* h2[3];
    h2[0] = (unsigned*)alloc(196608); h2[1] = (unsigned*)alloc(196608);
    h2[2] = (unsigned*)alloc(196608);
    float* c2 = alloc(196608);        // contiguous after h2[2] -> zeroB
    unsigned short* p2hi = (unsigned short*)alloc(196608);
    unsigned short* p2lo = (unsigned short*)alloc(196608);
    float* part = alloc(344064);
    unsigned short* w1F = (unsigned short*)alloc(24576);
    unsigned short* w2F = (unsigned short*)alloc(73728);
    unsigned short* w3F = (unsigned short*)alloc(2359296);
    float* w4T = alloc(32768);
    float* w5T = alloc(11264);
    (void)ws_size; (void)off;

    prep<<<2284, 256, 0, stream>>>(x, w1, w2, w3, w4, w5,
                                   h1[2], h2[2], xpk, w1F, w2F, w3F, w4T, w5T);

    for (int t = 0; t < 32; ++t) {
        // embedded lstm2 timestep: even t >= 4 -> tp=(t-4)/2 (0..13); t=31 -> 14
        int t2 = ((t & 1) == 0 && t >= 4) ? (t - 4) / 2 : (t == 31 ? 14 : -1);
        int nblk = (t2 >= 0) ? 768 : 512;
        step_k<<<nblk, 256, 0, stream>>>(
            xpk, w1F, b1, h1[(t + 2) % 3], h1[(t + 1) % 3], h1[t % 3], c1, p1pk,
            w2F, b2,
            t2 >= 0 ? h2[(t2 + 2) % 3] : h2[0],
            t2 >= 0 ? h2[(t2 + 1) % 3] : h2[0],
            t2 >= 0 ? h2[t2 % 3] : h2[0],
            c2, p2hi, p2lo, t, t2);
    }
    pool1k<<<512, 256, 0, stream>>>(h1[0], h1[1], p1pk, 15);     // h(30), h(31)

    // lstm2 tp=15: hprev=h2[(15+2)%3]=h2[2] (tp14), hpool=h2[1], hout=h2[0]
    lstm2_k<<<256, 256, 0, stream>>>(p1pk, w2F, b2, h2[2], h2[1], c2, h2[0],
                                     p2hi, p2lo, 15);
    pool2<<<192, 256, 0, stream>>>(h2[2], h2[0], p2hi, p2lo, 7); // h(14), h(15)

    conv3_part<<<dim3(16, 12), 256, 0, stream>>>(p2hi, p2lo, w3F, part);
    head<<<112, 256, 0, stream>>>(part, b3, w4T, b4, w5T, b5, out);
}